// Round 6
// baseline (243.391 us; speedup 1.0000x reference)
//
#include <hip/hip_runtime.h>
#include <hip/hip_cooperative_groups.h>

namespace cg = cooperative_groups;

namespace {

constexpr int kB = 8, kO = 128, kI = 128, kD = 1024;
constexpr long kOutAttnOff = (long)kB * kO * kD;   // 1,048,576 floats

typedef __attribute__((ext_vector_type(8))) short short8;  // 8 bf16 = 4 VGPR
typedef __attribute__((ext_vector_type(4))) float f32x4;

__device__ __forceinline__ float leaky(float x) { return fmaxf(x, 0.01f * x); }

// fp32 -> bf16 round-to-nearest-even
__device__ __forceinline__ short f2bf(float f) {
    unsigned u = __builtin_bit_cast(unsigned, f);
    u += 0x7FFFu + ((u >> 16) & 1u);
    return (short)(u >> 16);
}
__device__ __forceinline__ float bf2f(short h) {
    return __builtin_bit_cast(float, ((unsigned)(unsigned short)h) << 16);
}

// async global->LDS, 16B per lane. LDS dest = wave-uniform base + lane*16.
__device__ __forceinline__ void gll16(const void* g, void* l) {
    __builtin_amdgcn_global_load_lds(
        (const __attribute__((address_space(1))) int*)g,
        (__attribute__((address_space(3))) int*)l, 16, 0, 0);
}

struct Params {
    const float *output, *context; const int* mask;
    const float *w1, *w2, *w_b, *score_w, *score_b, *lin, *lin_b;
    float *out_main, *out_attn;
    short *ob16, *cb16, *w1t, *w2t, *lint;
    short *s_out16, *s_ctx16; float* outlin; short *ctxlin, *attn16;
};

// ===========================================================================
// ONE cooperative kernel, 512 blocks x 256 threads, 4 phases + 3 grid syncs.
// LDS union 48KB -> 2 blocks/CU -> all 512 blocks co-resident.
// ===========================================================================
__global__ __launch_bounds__(256, 2) void fused(Params p)
{
    __shared__ __align__(16) char smem[49152];
    cg::grid_group grid = cg::this_grid();
    const int bid = blockIdx.x, tid = threadIdx.x;
    const int lane = tid & 63, wv = tid >> 6;

    //================= Phase A: conversions (bf16 + transposes) =============
    {
        // straight conv: output (1M) + context (1M), 16 elems/thread
        const int idx = bid * 256 + tid;
        const float* src; short* dst; int i;
        if (idx < 65536) { src = p.output;  dst = p.ob16; i = idx; }
        else             { src = p.context; dst = p.cb16; i = idx - 65536; }
        const float4* s4 = (const float4*)src + (long)i * 4;
        const float4 v0 = s4[0], v1 = s4[1], v2 = s4[2], v3 = s4[3];
        short8 r0, r1;
        r0[0]=f2bf(v0.x); r0[1]=f2bf(v0.y); r0[2]=f2bf(v0.z); r0[3]=f2bf(v0.w);
        r0[4]=f2bf(v1.x); r0[5]=f2bf(v1.y); r0[6]=f2bf(v1.z); r0[7]=f2bf(v1.w);
        r1[0]=f2bf(v2.x); r1[1]=f2bf(v2.y); r1[2]=f2bf(v2.z); r1[3]=f2bf(v2.w);
        r1[4]=f2bf(v3.x); r1[5]=f2bf(v3.y); r1[6]=f2bf(v3.z); r1[7]=f2bf(v3.w);
        short8* d8 = (short8*)(dst + (long)i * 16);
        d8[0] = r0; d8[1] = r1;
    }
    {
        // transpose+convert: 1024 64x64 tile-jobs, 2 per block
        float (*T)[68] = reinterpret_cast<float(*)[68]>(smem);
        const int r = tid >> 2, q = tid & 3;
        for (int j = 0; j < 2; ++j) {
            const int tj = bid * 2 + j;
            const float* src; short* dst; long C, R; int t2;
            if (tj < 256)      { src = p.w1;  dst = p.w1t;  R = 1024; C = 1024; t2 = tj; }
            else if (tj < 512) { src = p.w2;  dst = p.w2t;  R = 1024; C = 1024; t2 = tj - 256; }
            else               { src = p.lin; dst = p.lint; R = 2048; C = 1024; t2 = tj - 512; }
            const int tr = t2 >> 4, tc = t2 & 15;
            const float* s = src + (long)(tr * 64 + r) * C + tc * 64 + q * 16;
            const float4 a0 = ((const float4*)s)[0];
            const float4 a1 = ((const float4*)s)[1];
            const float4 a2 = ((const float4*)s)[2];
            const float4 a3 = ((const float4*)s)[3];
            __syncthreads();           // protect T reads of previous job
            *(float4*)&T[r][q * 16 + 0]  = a0;
            *(float4*)&T[r][q * 16 + 4]  = a1;
            *(float4*)&T[r][q * 16 + 8]  = a2;
            *(float4*)&T[r][q * 16 + 12] = a3;
            __syncthreads();
            short8 o0, o1;
#pragma unroll
            for (int jj = 0; jj < 8; ++jj) o0[jj] = f2bf(T[q * 16 + jj][r]);
#pragma unroll
            for (int jj = 0; jj < 8; ++jj) o1[jj] = f2bf(T[q * 16 + 8 + jj][r]);
            short* dp = dst + (long)(tc * 64 + r) * R + tr * 64 + q * 16;
            *(short8*)dp       = o0;
            *((short8*)dp + 1) = o1;
        }
    }
    grid.sync();

    //================= Phase B: 4-job MFMA GEMM (64x128 tiles) ==============
    {
        short (*As)[64] = reinterpret_cast<short(*)[64]>(smem);           // [2*64][64]
        short (*Bs)[64] = reinterpret_cast<short(*)[64]>(smem + 16384);   // [2*128][64]
        const int t = bid;
        const short *Ap, *Bp;
        int lda, ldb, bm, bn, ldc;
        const float* bias = nullptr;
        float* Cf = nullptr; short* Ch = nullptr;

        if (t < 384) {
            const int job = t >> 7, jt = t & 127;
            bm = (jt >> 3) * 64; bn = (jt & 7) * 128; lda = 1024; ldc = 1024;
            if (job == 0)      { Ap = p.ob16; Bp = p.w1t;         ldb = 1024; bias = p.w_b;   Ch = p.s_out16; }
            else if (job == 1) { Ap = p.cb16; Bp = p.w2t;         ldb = 1024;                 Ch = p.s_ctx16; }
            else               { Ap = p.ob16; Bp = p.lint + 1024; ldb = 2048; bias = p.lin_b; Cf = p.outlin;  }
        } else {
            const int tt = t - 384, bz = tt >> 4, tw = tt & 15;
            bm = tw * 64; bn = 0;
            Ap = p.lint; lda = 2048;
            Bp = p.cb16 + (long)bz * (kI * kD); ldb = 1024;
            Ch = p.ctxlin + (long)bz * (kD * kI); ldc = 128;
        }

        const int m0 = (wv >> 1) * 32, n0 = (wv & 1) * 64;
        const int fr = lane & 15, fcol = lane >> 4, sl = lane & 7, r8 = lane >> 3;
        const int sw8 = ((lane & 7) ^ r8) * 8;   // swizzled source col (shorts)
        const int w16 = wv * 16, w32 = wv * 32;

        f32x4 acc[2][4] = {};
        auto stage = [&](int buf, int k0) {
            const short* ga = Ap + (long)(bm + w16 + r8) * lda + k0 + sw8;
            gll16(ga,                 &As[buf * 64 + w16][0]);
            gll16(ga + 8 * (long)lda, &As[buf * 64 + w16 + 8][0]);
            const short* gb = Bp + (long)(bn + w32 + r8) * ldb + k0 + sw8;
            gll16(gb,                  &Bs[buf * 128 + w32][0]);
            gll16(gb + 8 * (long)ldb,  &Bs[buf * 128 + w32 + 8][0]);
            gll16(gb + 16 * (long)ldb, &Bs[buf * 128 + w32 + 16][0]);
            gll16(gb + 24 * (long)ldb, &Bs[buf * 128 + w32 + 24][0]);
        };

        stage(0, 0);
        __syncthreads();
        int cur = 0;
        for (int s = 0; s < 16; ++s) {
            if (s < 15) stage(cur ^ 1, (s + 1) << 6);
#pragma unroll
            for (int ks8 = 0; ks8 < 8; ks8 += 4) {      // ks = 0, 32
                const int sa = ((ks8 + fcol) ^ sl) * 8; // swizzled read col
                short8 a[2], b[4];
#pragma unroll
                for (int mi = 0; mi < 2; ++mi)
                    a[mi] = *(const short8*)&As[cur * 64 + m0 + mi * 16 + fr][sa];
#pragma unroll
                for (int ni = 0; ni < 4; ++ni)
                    b[ni] = *(const short8*)&Bs[cur * 128 + n0 + ni * 16 + fr][sa];
#pragma unroll
                for (int mi = 0; mi < 2; ++mi)
#pragma unroll
                    for (int ni = 0; ni < 4; ++ni)
                        acc[mi][ni] = __builtin_amdgcn_mfma_f32_16x16x32_bf16(
                            a[mi], b[ni], acc[mi][ni], 0, 0, 0);
            }
            __syncthreads();
            cur ^= 1;
        }

        float bv[4] = {0, 0, 0, 0};
        if (bias) {
#pragma unroll
            for (int ni = 0; ni < 4; ++ni) bv[ni] = bias[bn + n0 + ni * 16 + fr];
        }
#pragma unroll
        for (int mi = 0; mi < 2; ++mi)
#pragma unroll
            for (int ni = 0; ni < 4; ++ni)
#pragma unroll
                for (int r = 0; r < 4; ++r) {
                    const int row = bm + m0 + mi * 16 + ((lane >> 4) << 2) + r;
                    const int col = bn + n0 + ni * 16 + fr;
                    const float v = acc[mi][ni][r] + bv[ni];
                    if (Ch) Ch[(long)row * ldc + col] = f2bf(v);
                    else    Cf[(long)row * ldc + col] = v;
                }
    }
    grid.sync();

    //================= Phase C: score + mask + softmax ======================
    {
        short (*Cs)[64] = reinterpret_cast<short(*)[64]>(smem);      // [2*128][64] bf16
        short* As2 = reinterpret_cast<short*>(smem + 32768);         // [2][1024] bf16
        float* Wsh = reinterpret_cast<float*>(smem + 36864);         // [1024]
        float* Ps  = reinterpret_cast<float*>(smem + 40960);         // [4][2][128]
        int*   Msk = reinterpret_cast<int*>(smem + 45056);           // [128]

        const int b = bid >> 6, o0 = (bid & 63) * 2;
        const int ln = lane;
        {
            const int r = tid >> 7, c8 = tid & 127;
            *(short8*)(As2 + r * 1024 + c8 * 8) =
                *(const short8*)(p.s_out16 + (long)(b * kO + o0 + r) * kD + c8 * 8);
        }
        *(float4*)&Wsh[tid * 4] = *(const float4*)&p.score_w[tid * 4];
        if (tid < 128) Msk[tid] = p.mask[b * kI + tid];

        const int kb = wv * 16;   // this wave's d-slice within each 64-chunk
        auto stageCs = [&](int buf, int dc) {
#pragma unroll
            for (int it = 0; it < 4; ++it) {
                const int base = wv * 32 + it * 8;
                const int rr = base + (lane >> 3);
                const int c16 = (lane & 7) ^ (rr & 7);   // swizzled source col
                gll16(p.s_ctx16 + (long)(b * kI + rr) * kD + dc + c16 * 8,
                      &Cs[buf * 128 + base][0]);
            }
        };

        float a00 = 0, a01 = 0, a10 = 0, a11 = 0;  // [o][i-half]
        stageCs(0, 0);
        __syncthreads();
        int buf = 0;
        for (int c = 0; c < 16; ++c) {
            const int dc = c * 64;
            if (c < 15) stageCs(buf ^ 1, dc + 64);
            // wave-uniform per-chunk preloads
            float wr[16], av0[16], av1[16];
            {
                const short8 x0 = *(const short8*)(As2 + dc + kb);
                const short8 x1 = *(const short8*)(As2 + dc + kb + 8);
                const short8 y0 = *(const short8*)(As2 + 1024 + dc + kb);
                const short8 y1 = *(const short8*)(As2 + 1024 + dc + kb + 8);
#pragma unroll
                for (int d = 0; d < 8; ++d) {
                    av0[d] = bf2f(x0[d]); av0[d + 8] = bf2f(x1[d]);
                    av1[d] = bf2f(y0[d]); av1[d + 8] = bf2f(y1[d]);
                }
#pragma unroll
                for (int q = 0; q < 4; ++q) {
                    const float4 ww = *(const float4*)&Wsh[dc + kb + q * 4];
                    wr[q*4] = ww.x; wr[q*4+1] = ww.y; wr[q*4+2] = ww.z; wr[q*4+3] = ww.w;
                }
            }
#pragma unroll
            for (int h = 0; h < 2; ++h) {
                const int i = ln + h * 64;
                const int sA = (((wv << 1) | 0) ^ (i & 7)) * 8;
                const int sB = (((wv << 1) | 1) ^ (i & 7)) * 8;
                const short8 cA = *(const short8*)&Cs[buf * 128 + i][sA];
                const short8 cB = *(const short8*)&Cs[buf * 128 + i][sB];
                float cf[16];
#pragma unroll
                for (int d = 0; d < 8; ++d) { cf[d] = bf2f(cA[d]); cf[d + 8] = bf2f(cB[d]); }
                float s0 = 0, s1 = 0;
#pragma unroll
                for (int d = 0; d < 16; ++d) {
                    s0 = fmaf(leaky(av0[d] + cf[d]), wr[d], s0);
                    s1 = fmaf(leaky(av1[d] + cf[d]), wr[d], s1);
                }
                if (h == 0) { a00 += s0; a10 += s1; }
                else        { a01 += s0; a11 += s1; }
            }
            __syncthreads();          // drains gll16 vmcnt + protects Cs
            buf ^= 1;
        }

        Ps[(wv * 2 + 0) * 128 + ln]      = a00;
        Ps[(wv * 2 + 0) * 128 + ln + 64] = a01;
        Ps[(wv * 2 + 1) * 128 + ln]      = a10;
        Ps[(wv * 2 + 1) * 128 + ln + 64] = a11;
        __syncthreads();

        if (wv < 2) {
            const int ow = wv;
            const float negInf = -__builtin_huge_valf();
            const float sb = p.score_b[0];
            float s0 = Ps[(0 + ow) * 128 + ln]       + Ps[(2 + ow) * 128 + ln]
                     + Ps[(4 + ow) * 128 + ln]       + Ps[(6 + ow) * 128 + ln]       + sb;
            float s1 = Ps[(0 + ow) * 128 + ln + 64]  + Ps[(2 + ow) * 128 + ln + 64]
                     + Ps[(4 + ow) * 128 + ln + 64]  + Ps[(6 + ow) * 128 + ln + 64]  + sb;
            if (Msk[ln]      != 0) s0 = negInf;
            if (Msk[ln + 64] != 0) s1 = negInf;

            float m = fmaxf(s0, s1);
#pragma unroll
            for (int d = 1; d < 64; d <<= 1) m = fmaxf(m, __shfl_xor(m, d, 64));
            const float e0 = __expf(s0 - m);
            const float e1 = __expf(s1 - m);
            float sum = e0 + e1;
#pragma unroll
            for (int d = 1; d < 64; d <<= 1) sum += __shfl_xor(sum, d, 64);
            const float inv = 1.0f / sum;

            const long rowoff = (long)(b * kO + o0 + ow) * kI;
            const float p0 = e0 * inv, p1 = e1 * inv;
            p.out_attn[rowoff + ln]      = p0;
            p.out_attn[rowoff + ln + 64] = p1;
            p.attn16[rowoff + ln]        = f2bf(p0);
            p.attn16[rowoff + ln + 64]   = f2bf(p1);
        }
    }
    grid.sync();

    //================= Phase D: final GEMM (256 active blocks) ==============
    if (bid < 256) {
        short (*As)[64] = reinterpret_cast<short(*)[64]>(smem);          // [2*64][64]
        short (*Bs)[64] = reinterpret_cast<short(*)[64]>(smem + 16384);  // [2*64][64]
        const int z = bid >> 5, tile = bid & 31;
        const int bm = (tile >> 4) * 64, bn = (tile & 15) * 64;
        const short* Az = p.attn16 + (long)z * (kO * kI);
        const short* Bz = p.ctxlin + (long)z * (kD * kI);
        const float* adz = p.outlin + (long)z * (kO * kD);
        float* Cz = p.out_main + (long)z * (kO * kD);

        const int m0 = (wv >> 1) * 32, n0 = (wv & 1) * 32;
        const int fr = lane & 15, fcol = lane >> 4, sl = lane & 7, r8 = lane >> 3;
        const int sw8 = ((lane & 7) ^ r8) * 8;
        const int w16 = wv * 16;

        f32x4 acc[2][2] = {};
        auto stage = [&](int buf, int k0) {
            const short* ga = Az + (long)(bm + w16 + r8) * kI + k0 + sw8;
            gll16(ga,          &As[buf * 64 + w16][0]);
            gll16(ga + 8 * kI, &As[buf * 64 + w16 + 8][0]);
            const short* gb = Bz + (long)(bn + w16 + r8) * kI + k0 + sw8;
            gll16(gb,          &Bs[buf * 64 + w16][0]);
            gll16(gb + 8 * kI, &Bs[buf * 64 + w16 + 8][0]);
        };

        stage(0, 0);
        __syncthreads();
        int cur = 0;
        for (int s = 0; s < 2; ++s) {
            if (s == 0) stage(1, 64);
#pragma unroll
            for (int ks8 = 0; ks8 < 8; ks8 += 4) {
                const int sa = ((ks8 + fcol) ^ sl) * 8;
                const short8 a0 = *(const short8*)&As[cur * 64 + m0 + fr][sa];
                const short8 a1 = *(const short8*)&As[cur * 64 + m0 + 16 + fr][sa];
                const short8 b0 = *(const short8*)&Bs[cur * 64 + n0 + fr][sa];
                const short8 b1 = *(const short8*)&Bs[cur * 64 + n0 + 16 + fr][sa];
                acc[0][0] = __builtin_amdgcn_mfma_f32_16x16x32_bf16(a0, b0, acc[0][0], 0, 0, 0);
                acc[0][1] = __builtin_amdgcn_mfma_f32_16x16x32_bf16(a0, b1, acc[0][1], 0, 0, 0);
                acc[1][0] = __builtin_amdgcn_mfma_f32_16x16x32_bf16(a1, b0, acc[1][0], 0, 0, 0);
                acc[1][1] = __builtin_amdgcn_mfma_f32_16x16x32_bf16(a1, b1, acc[1][1], 0, 0, 0);
            }
            __syncthreads();
            cur ^= 1;
        }

#pragma unroll
        for (int mi = 0; mi < 2; ++mi)
#pragma unroll
            for (int ni = 0; ni < 2; ++ni)
#pragma unroll
                for (int r = 0; r < 4; ++r) {
                    const int row = bm + m0 + mi * 16 + ((lane >> 4) << 2) + r;
                    const int col = bn + n0 + ni * 16 + fr;
                    Cz[(long)row * kD + col] =
                        leaky(acc[mi][ni][r] + adz[(long)row * kD + col]);
                }
    }
}

} // namespace

extern "C" void kernel_launch(void* const* d_in, const int* in_sizes, int n_in,
                              void* d_out, int out_size, void* d_ws, size_t ws_size,
                              hipStream_t stream)
{
    const float* output  = (const float*)d_in[0];   // [B,O,D]
    const float* context = (const float*)d_in[1];   // [B,I,D]
    const int*   mask    = (const int*)d_in[2];     // [B,I]
    const float* w_out_w = (const float*)d_in[3];   // [D,D]
    const float* w_ctx_w = (const float*)d_in[4];   // [D,D]
    const float* w_b     = (const float*)d_in[5];   // [D]
    const float* score_w = (const float*)d_in[6];   // [D]
    const float* score_b = (const float*)d_in[7];   // scalar
    const float* lin_w   = (const float*)d_in[8];   // [2D,D]
    const float* lin_b   = (const float*)d_in[9];   // [D]

    float* out_main = (float*)d_out;                 // [B,O,D]
    float* out_attn = out_main + kOutAttnOff;        // [B,O,I]

    char* wp = (char*)d_ws;
    short* ob16    = (short*)wp;  wp += (size_t)2 << 20;  // output bf16
    short* cb16    = (short*)wp;  wp += (size_t)2 << 20;  // context bf16
    short* w1t     = (short*)wp;  wp += (size_t)2 << 20;  // w_out_w^T bf16
    short* w2t     = (short*)wp;  wp += (size_t)2 << 20;  // w_ctx_w^T bf16
    short* lint    = (short*)wp;  wp += (size_t)4 << 20;  // lin_w^T bf16 [1024][2048]
    short* s_out16 = (short*)wp;  wp += (size_t)2 << 20;  // s_out bf16
    short* s_ctx16 = (short*)wp;  wp += (size_t)2 << 20;  // s_ctx bf16
    float* outlin  = (float*)wp;  wp += (size_t)4 << 20;  // output@lin_bot+lin_b fp32
    short* ctxlin  = (short*)wp;  wp += (size_t)2 << 20;  // (ctx@lin_top)^T bf16
    short* attn16  = (short*)wp;                          // 256 KB bf16 attn

    Params prm;
    prm.output = output; prm.context = context; prm.mask = mask;
    prm.w1 = w_out_w; prm.w2 = w_ctx_w; prm.w_b = w_b;
    prm.score_w = score_w; prm.score_b = score_b;
    prm.lin = lin_w; prm.lin_b = lin_b;
    prm.out_main = out_main; prm.out_attn = out_attn;
    prm.ob16 = ob16; prm.cb16 = cb16; prm.w1t = w1t; prm.w2t = w2t; prm.lint = lint;
    prm.s_out16 = s_out16; prm.s_ctx16 = s_ctx16; prm.outlin = outlin;
    prm.ctxlin = ctxlin; prm.attn16 = attn16;

    void* args[] = { &prm };
    hipLaunchCooperativeKernel((const void*)fused, dim3(512), dim3(256),
                               args, 0, stream);
}

// Round 7
// 72.296 us; speedup vs baseline: 3.3666x; 3.3666x over previous
//
#include <hip/hip_runtime.h>

namespace {

constexpr int kB = 8, kO = 128, kI = 128, kD = 1024;
constexpr long kOutAttnOff = (long)kB * kO * kD;   // 1,048,576 floats

typedef __attribute__((ext_vector_type(8))) short short8;  // 8 bf16 = 4 VGPR
typedef __attribute__((ext_vector_type(4))) float f32x4;

__device__ __forceinline__ float leaky(float x) { return fmaxf(x, 0.01f * x); }

// fp32 -> bf16 round-to-nearest-even
__device__ __forceinline__ short f2bf(float f) {
    unsigned u = __builtin_bit_cast(unsigned, f);
    u += 0x7FFFu + ((u >> 16) & 1u);
    return (short)(u >> 16);
}

// async global->LDS, 16B per lane. LDS dest = wave-uniform base + lane*16.
__device__ __forceinline__ void gll16(const void* g, void* l) {
    __builtin_amdgcn_global_load_lds(
        (const __attribute__((address_space(1))) int*)g,
        (__attribute__((address_space(3))) int*)l, 16, 0, 0);
}

// ---------------------------------------------------------------------------
// All input conversions in ONE kernel (identical to round 5).
// ---------------------------------------------------------------------------
__global__ __launch_bounds__(256)
void conv_all(const float* __restrict__ output, const float* __restrict__ context,
              const float* __restrict__ w1, const float* __restrict__ w2,
              const float* __restrict__ lin,
              short* __restrict__ ob16, short* __restrict__ cb16,
              short* __restrict__ w1t, short* __restrict__ w2t,
              short* __restrict__ lint)
{
    __shared__ float T[64][68];
    const int bid = blockIdx.x, tid = threadIdx.x;

    if (bid < 1024) {                       // straight convert, 8 floats/thread
        const int idx = bid * 256 + tid;
        const float* src; short* dst; int i;
        if (idx < (1 << 17)) { src = output;  dst = ob16; i = idx; }
        else                 { src = context; dst = cb16; i = idx - (1 << 17); }
        const float4* s4 = (const float4*)src + (long)i * 2;
        const float4 v0 = s4[0], v1 = s4[1];
        short8 r;
        r[0] = f2bf(v0.x); r[1] = f2bf(v0.y); r[2] = f2bf(v0.z); r[3] = f2bf(v0.w);
        r[4] = f2bf(v1.x); r[5] = f2bf(v1.y); r[6] = f2bf(v1.z); r[7] = f2bf(v1.w);
        *(short8*)(dst + (long)i * 8) = r;
        return;
    }

    const int tb = bid - 1024;
    const float* src; short* dst; long C, R; int t2;
    if (tb < 256)      { src = w1;  dst = w1t;  R = 1024; C = 1024; t2 = tb; }
    else if (tb < 512) { src = w2;  dst = w2t;  R = 1024; C = 1024; t2 = tb - 256; }
    else               { src = lin; dst = lint; R = 2048; C = 1024; t2 = tb - 512; }
    const int tr = t2 >> 4, tc = t2 & 15;
    const int r = tid >> 2, q = tid & 3;

    const float* s = src + (long)(tr * 64 + r) * C + tc * 64 + q * 16;
    const float4 a0 = ((const float4*)s)[0];
    const float4 a1 = ((const float4*)s)[1];
    const float4 a2 = ((const float4*)s)[2];
    const float4 a3 = ((const float4*)s)[3];
    *(float4*)&T[r][q * 16 + 0]  = a0;
    *(float4*)&T[r][q * 16 + 4]  = a1;
    *(float4*)&T[r][q * 16 + 8]  = a2;
    *(float4*)&T[r][q * 16 + 12] = a3;
    __syncthreads();

    short8 o0, o1;
#pragma unroll
    for (int j = 0; j < 8; ++j)  o0[j] = f2bf(T[q * 16 + j][r]);
#pragma unroll
    for (int j = 0; j < 8; ++j)  o1[j] = f2bf(T[q * 16 + 8 + j][r]);
    short* dp = dst + (long)(tc * 64 + r) * R + tr * 64 + q * 16;
    *(short8*)dp       = o0;
    *((short8*)dp + 1) = o1;
}

// ---------------------------------------------------------------------------
// Fused independent-GEMM job table (identical to round 5). 512 blocks.
// ---------------------------------------------------------------------------
__global__ __launch_bounds__(256)
void mm_jobs(const short* __restrict__ ob16, const short* __restrict__ cb16,
             const short* __restrict__ w1t, const short* __restrict__ w2t,
             const short* __restrict__ lint,
             const float* __restrict__ w_b, const float* __restrict__ lin_b,
             float* __restrict__ s_out, float* __restrict__ s_ctx,
             float* __restrict__ outlin, short* __restrict__ ctxlin)
{
    __shared__ short As[2][64][64];
    __shared__ short Bs[2][128][64];
    const int tid = threadIdx.x;
    const int t = blockIdx.x;
    const int lane = tid & 63, w = tid >> 6;

    const short *Ap, *Bp;
    int lda, ldb, bm, bn, ldc;
    const float* bias = nullptr;
    float* Cf = nullptr;
    short* Ch = nullptr;

    if (t < 384) {
        const int job = t >> 7, jt = t & 127;
        bm = (jt >> 3) * 64; bn = (jt & 7) * 128;
        lda = 1024; ldc = 1024;
        if (job == 0)      { Ap = ob16; Bp = w1t;         ldb = 1024; bias = w_b;   Cf = s_out;  }
        else if (job == 1) { Ap = cb16; Bp = w2t;         ldb = 1024;               Cf = s_ctx;  }
        else               { Ap = ob16; Bp = lint + 1024; ldb = 2048; bias = lin_b; Cf = outlin; }
    } else {
        const int tt = t - 384, bz = tt >> 4, tw = tt & 15;
        bm = tw * 64; bn = 0;
        Ap = lint; lda = 2048;
        Bp = cb16 + (long)bz * (kI * kD); ldb = 1024;
        Ch = ctxlin + (long)bz * (kD * kI); ldc = 128;
    }

    const int m0 = (w >> 1) * 32, n0 = (w & 1) * 64;
    const int fr = lane & 15, fcol = lane >> 4, sl = lane & 7;
    const int r8 = lane >> 3;
    const int sw8 = ((lane & 7) ^ r8) * 8;   // swizzled source col (shorts)
    const int w16 = w * 16, w32 = w * 32;

    f32x4 acc[2][4] = {};

    auto stage = [&](int buf, int k0) {
        const short* ga = Ap + (long)(bm + w16 + r8) * lda + k0 + sw8;
        gll16(ga,                 &As[buf][w16][0]);
        gll16(ga + 8 * (long)lda, &As[buf][w16 + 8][0]);
        const short* gb = Bp + (long)(bn + w32 + r8) * ldb + k0 + sw8;
        gll16(gb,                  &Bs[buf][w32][0]);
        gll16(gb + 8 * (long)ldb,  &Bs[buf][w32 + 8][0]);
        gll16(gb + 16 * (long)ldb, &Bs[buf][w32 + 16][0]);
        gll16(gb + 24 * (long)ldb, &Bs[buf][w32 + 24][0]);
    };

    stage(0, 0);
    __syncthreads();
    int cur = 0;
    for (int s = 0; s < 16; ++s) {
        if (s < 15) stage(cur ^ 1, (s + 1) << 6);
#pragma unroll
        for (int ks8 = 0; ks8 < 8; ks8 += 4) {      // ks = 0, 32
            const int sa = ((ks8 + fcol) ^ sl) * 8; // swizzled read col (shorts)
            short8 a[2], b[4];
#pragma unroll
            for (int mi = 0; mi < 2; ++mi)
                a[mi] = *(const short8*)&As[cur][m0 + mi * 16 + fr][sa];
#pragma unroll
            for (int ni = 0; ni < 4; ++ni)
                b[ni] = *(const short8*)&Bs[cur][n0 + ni * 16 + fr][sa];
#pragma unroll
            for (int mi = 0; mi < 2; ++mi)
#pragma unroll
                for (int ni = 0; ni < 4; ++ni)
                    acc[mi][ni] = __builtin_amdgcn_mfma_f32_16x16x32_bf16(
                        a[mi], b[ni], acc[mi][ni], 0, 0, 0);
        }
        __syncthreads();
        cur ^= 1;
    }

    float bv[4] = {0, 0, 0, 0};
    if (bias) {
#pragma unroll
        for (int ni = 0; ni < 4; ++ni) bv[ni] = bias[bn + n0 + ni * 16 + fr];
    }
#pragma unroll
    for (int mi = 0; mi < 2; ++mi)
#pragma unroll
        for (int ni = 0; ni < 4; ++ni)
#pragma unroll
            for (int r = 0; r < 4; ++r) {
                const int row = bm + m0 + mi * 16 + ((lane >> 4) << 2) + r;
                const int col = bn + n0 + ni * 16 + fr;
                float v = acc[mi][ni][r] + bv[ni];
                if (Ch) Ch[(long)row * ldc + col] = f2bf(v);
                else    Cf[(long)row * ldc + col] = v;
            }
}

// ---------------------------------------------------------------------------
// Fused score + mask + softmax + FINAL GEMM. Block = (b, o-quad): 256 blocks.
// Score: leaky(x)=0.505x+0.495|x| -> score = 0.505(so[o]+si[i]) + 0.495 sa
//   so[o]=sum_d s_out*w (once/block), si[i]=sum_d c*w (0.25 op/elem),
//   sa=sum_d |av+c|*w (3 ops/elem). 4 waves = 4 d-quarters as in round 5.
// Final: out[b,o0+r,:] = leaky(P @ ctxlin[b]^T + outlin) via MFMA with
//   P zero-padded 4->16 rows; ctxlin staged in LDS (swizzled gll16).
// ---------------------------------------------------------------------------
__global__ __launch_bounds__(256)
void score_final(const float* __restrict__ s_out, const float* __restrict__ s_ctx,
                 const float* __restrict__ score_w, const float* __restrict__ score_b,
                 const int* __restrict__ mask, const short* __restrict__ ctxlin,
                 const float* __restrict__ outlin, float* __restrict__ out_main,
                 float* __restrict__ attn_f32)
{
    __shared__ float As[4][1032];
    __shared__ __align__(16) char CsPool[65536];   // score: 2x[128][64] f32; final: 2x[128][128] bf16
    __shared__ float Wsh[1024];
    __shared__ float Ps[4][4][128];    // sa partials [d-quarter][o][i]
    __shared__ float Psi[4][128];      // si partials [d-quarter][i]
    __shared__ float so_sh[4];
    __shared__ int   Msk[128];
    __shared__ short Pl[16][136];      // attn rows, zero-padded to 16, +8 pad

    float (*Cs)[128][64] = reinterpret_cast<float(*)[128][64]>(CsPool);
    const int b   = blockIdx.x;
    const int o0  = blockIdx.y * 4;
    const int tid = threadIdx.x;
    const int wv  = tid >> 6;          // d-quarter (wave-uniform)
    const int ln  = tid & 63;          // i low half; also owns i+64
    const int fr  = ln & 15;

    // ---- stage As (4 o-rows of s_out), Wsh, Msk; zero Pl ----
    const float* arow = s_out + (long)(b * kO + o0) * kD;
#pragma unroll
    for (int q = 0; q < 4; ++q) {
        const int tq = tid + q * 256;
        const int rr = tq >> 8, c4 = (tq & 255) * 4;
        *(float4*)&As[rr][c4] = *(const float4*)&arow[(long)rr * kD + c4];
    }
    *(float4*)&Wsh[tid * 4] = *(const float4*)&score_w[tid * 4];
    if (tid < 128) Msk[tid] = mask[b * kI + tid];
    {
        short* pf = &Pl[0][0];                     // 16*136 = 2176 shorts
        for (int j = tid; j < 272; j += 256) *(short8*)(pf + j * 8) = short8{};
    }

    const float* crow = s_ctx + (long)b * kI * kD;
    const int srow = wv * 4 + (ln >> 4);            // staging row (+ it*16)
    const int cho  = ((ln & 15) ^ (srow & 7)) * 4;  // pre-swizzled source col

    auto stageCs = [&](int buf, int dc) {
#pragma unroll
        for (int it = 0; it < 8; ++it)
            gll16(crow + (long)(srow + it * 16) * kD + dc + cho,
                  &Cs[buf][wv * 4 + it * 16][0]);
    };

    stageCs(0, 0);
    __syncthreads();

    // ---- so[o] = sum_d s_out[o,d]*w[d], wave wv handles o=wv ----
    {
        float acc = 0.0f;
#pragma unroll
        for (int j = 0; j < 16; j += 4) {
            const float4 av = *(const float4*)&As[wv][ln * 16 + j];
            const float4 ww = *(const float4*)&Wsh[ln * 16 + j];
            acc = fmaf(av.x, ww.x, acc); acc = fmaf(av.y, ww.y, acc);
            acc = fmaf(av.z, ww.z, acc); acc = fmaf(av.w, ww.w, acc);
        }
#pragma unroll
        for (int d = 1; d < 64; d <<= 1) acc += __shfl_xor(acc, d, 64);
        if (ln == 0) so_sh[wv] = acc;
    }

    // ---- main loop: sa (abs part) + si ----
    float sa0[4] = {}, sa1[4] = {};
    float si0 = 0.0f, si1 = 0.0f;
    const int kb = wv * 16;            // this wave's d-slice within each chunk

    int buf = 0;
    for (int c = 0; c < 16; ++c) {
        const int dc = c * 64;
        if (c < 15) stageCs(buf ^ 1, dc + 64);
#pragma unroll
        for (int kq = 0; kq < 4; ++kq) {
            const int sc = ((wv * 4 + kq) ^ (ln & 7)) * 4;   // swizzled read
            const float4 c0 = *(const float4*)&Cs[buf][ln][sc];
            const float4 c1 = *(const float4*)&Cs[buf][ln + 64][sc];
            const float4 w4 = *(const float4*)&Wsh[dc + kb + kq * 4];
            si0 = fmaf(c0.x, w4.x, si0); si0 = fmaf(c0.y, w4.y, si0);
            si0 = fmaf(c0.z, w4.z, si0); si0 = fmaf(c0.w, w4.w, si0);
            si1 = fmaf(c1.x, w4.x, si1); si1 = fmaf(c1.y, w4.y, si1);
            si1 = fmaf(c1.z, w4.z, si1); si1 = fmaf(c1.w, w4.w, si1);
#pragma unroll
            for (int o = 0; o < 4; ++o) {
                const float4 av = *(const float4*)&As[o][dc + kb + kq * 4];
                sa0[o] = fmaf(__builtin_fabsf(av.x + c0.x), w4.x, sa0[o]);
                sa0[o] = fmaf(__builtin_fabsf(av.y + c0.y), w4.y, sa0[o]);
                sa0[o] = fmaf(__builtin_fabsf(av.z + c0.z), w4.z, sa0[o]);
                sa0[o] = fmaf(__builtin_fabsf(av.w + c0.w), w4.w, sa0[o]);
                sa1[o] = fmaf(__builtin_fabsf(av.x + c1.x), w4.x, sa1[o]);
                sa1[o] = fmaf(__builtin_fabsf(av.y + c1.y), w4.y, sa1[o]);
                sa1[o] = fmaf(__builtin_fabsf(av.z + c1.z), w4.z, sa1[o]);
                sa1[o] = fmaf(__builtin_fabsf(av.w + c1.w), w4.w, sa1[o]);
            }
        }
        __syncthreads();               // drains gll16 vmcnt + protects Cs
        buf ^= 1;
    }

#pragma unroll
    for (int o = 0; o < 4; ++o) {
        Ps[wv][o][ln]      = sa0[o];
        Ps[wv][o][ln + 64] = sa1[o];
    }
    Psi[wv][ln]      = si0;
    Psi[wv][ln + 64] = si1;
    __syncthreads();

    // ---- combine + mask + softmax; wave wv handles o-row ow=wv ----
    {
        const int ow = wv;
        const float negInf = -__builtin_huge_valf();
        const float sb = score_b[0];
        const float siT0 = Psi[0][ln] + Psi[1][ln] + Psi[2][ln] + Psi[3][ln];
        const float siT1 = Psi[0][ln + 64] + Psi[1][ln + 64]
                         + Psi[2][ln + 64] + Psi[3][ln + 64];
        const float saT0 = Ps[0][ow][ln] + Ps[1][ow][ln]
                         + Ps[2][ow][ln] + Ps[3][ow][ln];
        const float saT1 = Ps[0][ow][ln + 64] + Ps[1][ow][ln + 64]
                         + Ps[2][ow][ln + 64] + Ps[3][ow][ln + 64];
        const float soV = so_sh[ow];
        float s0 = 0.505f * (soV + siT0) + 0.495f * saT0 + sb;
        float s1 = 0.505f * (soV + siT1) + 0.495f * saT1 + sb;
        if (Msk[ln]      != 0) s0 = negInf;
        if (Msk[ln + 64] != 0) s1 = negInf;

        float m = fmaxf(s0, s1);
#pragma unroll
        for (int d = 1; d < 64; d <<= 1) m = fmaxf(m, __shfl_xor(m, d, 64));
        const float e0 = __expf(s0 - m);
        const float e1 = __expf(s1 - m);
        float sum = e0 + e1;
#pragma unroll
        for (int d = 1; d < 64; d <<= 1) sum += __shfl_xor(sum, d, 64);
        const float inv = 1.0f / sum;

        const long rowoff = (long)(b * kO + o0 + ow) * kI;
        const float p0 = e0 * inv, p1 = e1 * inv;
        attn_f32[rowoff + ln]      = p0;
        attn_f32[rowoff + ln + 64] = p1;
        Pl[ow][ln]      = f2bf(p0);
        Pl[ow][ln + 64] = f2bf(p1);
    }

    // ---- final GEMM: out[b,o0+r,:] = leaky(P @ ctxlin^T + outlin) ----
    short* Bsh = (short*)CsPool;               // 2 halves of [128][128] bf16
    const short* ctxb = ctxlin + (long)b * (kD * kI);
    auto stageB = [&](int half, int nc) {
        short* dst = Bsh + half * (128 * 128);
#pragma unroll
        for (int it = 0; it < 8; ++it) {
            const int rb = wv * 32 + it * 4;           // block-local row base
            const int r  = rb + (ln >> 4);             // 0..127
            const int gn = nc * 128 + r;               // global n row
            const int sc = (ln & 15) ^ (r & 7);        // src chunk (16B units)
            gll16(ctxb + (long)gn * kI + sc * 8, dst + rb * 128);
        }
    };

    stageB(0, 0);
    __syncthreads();                   // Pl visible + Bsh[0] ready
    int half = 0;
    const int fg = ln >> 4;            // k-group
    for (int nc = 0; nc < 8; ++nc) {
        if (nc < 7) stageB(half ^ 1, nc + 1);
        const short* Bc = Bsh + half * (128 * 128);
        f32x4 accT0{}, accT1{};
#pragma unroll
        for (int ks = 0; ks < 4; ++ks) {
            const short8 a = *(const short8*)&Pl[fr][ks * 32 + fg * 8];
            const int n0 = (wv * 2) * 16 + fr;
            const int n1 = (wv * 2 + 1) * 16 + fr;
            const int ch0 = ((ks * 4 + fg) ^ (n0 & 7)) * 8;
            const int ch1 = ((ks * 4 + fg) ^ (n1 & 7)) * 8;
            const short8 b0 = *(const short8*)&Bc[n0 * 128 + ch0];
            const short8 b1 = *(const short8*)&Bc[n1 * 128 + ch1];
            accT0 = __builtin_amdgcn_mfma_f32_16x16x32_bf16(a, b0, accT0, 0, 0, 0);
            accT1 = __builtin_amdgcn_mfma_f32_16x16x32_bf16(a, b1, accT1, 0, 0, 0);
        }
        if (fg == 0) {                 // lanes 0..15 hold rows 0..3 in regs 0..3
#pragma unroll
            for (int r = 0; r < 4; ++r) {
                const long off = (long)(b * kO + o0 + r) * kD;
                const int na = nc * 128 + (wv * 2) * 16 + fr;
                const int nb = nc * 128 + (wv * 2 + 1) * 16 + fr;
                out_main[off + na] = leaky(accT0[r] + outlin[off + na]);
                out_main[off + nb] = leaky(accT1[r] + outlin[off + nb]);
            }
        }
        __syncthreads();
        half ^= 1;
    }
}

} // namespace

extern "C" void kernel_launch(void* const* d_in, const int* in_sizes, int n_in,
                              void* d_out, int out_size, void* d_ws, size_t ws_size,
                              hipStream_t stream)
{
    const float* output  = (const float*)d_in[0];   // [B,O,D]
    const float* context = (const float*)d_in[1];   // [B,I,D]
    const int*   mask    = (const int*)d_in[2];     // [B,I]
    const float* w_out_w = (const float*)d_in[3];   // [D,D]
    const float* w_ctx_w = (const float*)d_in[4];   // [D,D]
    const float* w_b     = (const float*)d_in[5];   // [D]
    const float* score_w = (const float*)d_in[6];   // [D]
    const float* score_b = (const float*)d_in[7];   // scalar
    const float* lin_w   = (const float*)d_in[8];   // [2D,D]
    const float* lin_b   = (const float*)d_in[9];   // [D]

    float* out_main = (float*)d_out;                 // [B,O,D]
    float* out_attn = out_main + kOutAttnOff;        // [B,O,I]
    float* s_out    = out_main;                      // overlay: each score block
                                                     // reads its 4 rows before
                                                     // writing them at the end

    char* wp = (char*)d_ws;
    float* s_ctx  = (float*)wp;  wp += (size_t)4 << 20;  // fp32 [B*I][D]
    short* ob16   = (short*)wp;  wp += (size_t)2 << 20;  // output bf16
    short* cb16   = (short*)wp;  wp += (size_t)2 << 20;  // context bf16
    short* w1t    = (short*)wp;  wp += (size_t)2 << 20;  // w_out_w^T bf16
    short* w2t    = (short*)wp;  wp += (size_t)2 << 20;  // w_ctx_w^T bf16
    short* lint   = (short*)wp;  wp += (size_t)4 << 20;  // lin_w^T bf16 [1024][2048]
    float* outlin = (float*)wp;  wp += (size_t)4 << 20;  // output@lin_bot+lin_b fp32
    short* ctxlin = (short*)wp;  wp += (size_t)2 << 20;  // (ctx@lin_top)^T bf16 [b][1024][128]

    const dim3 blk(256);

    // 1) all conversions
    hipLaunchKernelGGL(conv_all, dim3(2048), blk, 0, stream,
        output, context, w_out_w, w_ctx_w, lin_w, ob16, cb16, w1t, w2t, lint);

    // 2) all input-independent GEMMs in one 512-block launch
    hipLaunchKernelGGL(mm_jobs, dim3(512), blk, 0, stream,
        ob16, cb16, w1t, w2t, lint, w_b, lin_b, s_out, s_ctx, outlin, ctxlin);

    // 3) score + softmax + final GEMM fused (256 blocks)
    hipLaunchKernelGGL(score_final, dim3(8, 32), blk, 0, stream,
        s_out, s_ctx, score_w, score_b, mask, ctxlin, outlin, out_main, out_attn);
}

// Round 8
// 64.565 us; speedup vs baseline: 3.7697x; 1.1197x over previous
//
#include <hip/hip_runtime.h>

namespace {

constexpr int kB = 8, kO = 128, kI = 128, kD = 1024;
constexpr long kOutAttnOff = (long)kB * kO * kD;   // 1,048,576 floats

typedef __attribute__((ext_vector_type(8))) short short8;  // 8 bf16 = 4 VGPR
typedef __attribute__((ext_vector_type(4))) float f32x4;

__device__ __forceinline__ float leaky(float x) { return fmaxf(x, 0.01f * x); }

// fp32 -> bf16 round-to-nearest-even
__device__ __forceinline__ short f2bf(float f) {
    unsigned u = __builtin_bit_cast(unsigned, f);
    u += 0x7FFFu + ((u >> 16) & 1u);
    return (short)(u >> 16);
}

// short8 of bf16 -> 8 f32 (1 op per value: shl / and)
__device__ __forceinline__ void b8tof(const short8 v, float* f) {
    const unsigned* u = (const unsigned*)&v;
#pragma unroll
    for (int j = 0; j < 4; ++j) {
        f[2 * j]     = __builtin_bit_cast(float, u[j] << 16);
        f[2 * j + 1] = __builtin_bit_cast(float, u[j] & 0xffff0000u);
    }
}

// async global->LDS, 16B per lane. LDS dest = wave-uniform base + lane*16.
__device__ __forceinline__ void gll16(const void* g, void* l) {
    __builtin_amdgcn_global_load_lds(
        (const __attribute__((address_space(1))) int*)g,
        (__attribute__((address_space(3))) int*)l, 16, 0, 0);
}

// ---------------------------------------------------------------------------
// All input conversions in ONE kernel (identical to round 5/7).
// ---------------------------------------------------------------------------
__global__ __launch_bounds__(256)
void conv_all(const float* __restrict__ output, const float* __restrict__ context,
              const float* __restrict__ w1, const float* __restrict__ w2,
              const float* __restrict__ lin,
              short* __restrict__ ob16, short* __restrict__ cb16,
              short* __restrict__ w1t, short* __restrict__ w2t,
              short* __restrict__ lint)
{
    __shared__ float T[64][68];
    const int bid = blockIdx.x, tid = threadIdx.x;

    if (bid < 1024) {                       // straight convert, 8 floats/thread
        const int idx = bid * 256 + tid;
        const float* src; short* dst; int i;
        if (idx < (1 << 17)) { src = output;  dst = ob16; i = idx; }
        else                 { src = context; dst = cb16; i = idx - (1 << 17); }
        const float4* s4 = (const float4*)src + (long)i * 2;
        const float4 v0 = s4[0], v1 = s4[1];
        short8 r;
        r[0] = f2bf(v0.x); r[1] = f2bf(v0.y); r[2] = f2bf(v0.z); r[3] = f2bf(v0.w);
        r[4] = f2bf(v1.x); r[5] = f2bf(v1.y); r[6] = f2bf(v1.z); r[7] = f2bf(v1.w);
        *(short8*)(dst + (long)i * 8) = r;
        return;
    }

    const int tb = bid - 1024;
    const float* src; short* dst; long C, R; int t2;
    if (tb < 256)      { src = w1;  dst = w1t;  R = 1024; C = 1024; t2 = tb; }
    else if (tb < 512) { src = w2;  dst = w2t;  R = 1024; C = 1024; t2 = tb - 256; }
    else               { src = lin; dst = lint; R = 2048; C = 1024; t2 = tb - 512; }
    const int tr = t2 >> 4, tc = t2 & 15;
    const int r = tid >> 2, q = tid & 3;

    const float* s = src + (long)(tr * 64 + r) * C + tc * 64 + q * 16;
    const float4 a0 = ((const float4*)s)[0];
    const float4 a1 = ((const float4*)s)[1];
    const float4 a2 = ((const float4*)s)[2];
    const float4 a3 = ((const float4*)s)[3];
    *(float4*)&T[r][q * 16 + 0]  = a0;
    *(float4*)&T[r][q * 16 + 4]  = a1;
    *(float4*)&T[r][q * 16 + 8]  = a2;
    *(float4*)&T[r][q * 16 + 12] = a3;
    __syncthreads();

    short8 o0, o1;
#pragma unroll
    for (int j = 0; j < 8; ++j)  o0[j] = f2bf(T[q * 16 + j][r]);
#pragma unroll
    for (int j = 0; j < 8; ++j)  o1[j] = f2bf(T[q * 16 + 8 + j][r]);
    short* dp = dst + (long)(tc * 64 + r) * R + tr * 64 + q * 16;
    *(short8*)dp       = o0;
    *((short8*)dp + 1) = o1;
}

// ---------------------------------------------------------------------------
// Fused independent-GEMM job table, 512 blocks (as round 5/7); job1 now
// writes s_ctx in bf16 (halves score-kernel staging bytes + LDS).
// ---------------------------------------------------------------------------
__global__ __launch_bounds__(256)
void mm_jobs(const short* __restrict__ ob16, const short* __restrict__ cb16,
             const short* __restrict__ w1t, const short* __restrict__ w2t,
             const short* __restrict__ lint,
             const float* __restrict__ w_b, const float* __restrict__ lin_b,
             float* __restrict__ s_out, short* __restrict__ s_ctx16,
             float* __restrict__ outlin, short* __restrict__ ctxlin)
{
    __shared__ short As[2][64][64];
    __shared__ short Bs[2][128][64];
    const int tid = threadIdx.x;
    const int t = blockIdx.x;
    const int lane = tid & 63, w = tid >> 6;

    const short *Ap, *Bp;
    int lda, ldb, bm, bn, ldc;
    const float* bias = nullptr;
    float* Cf = nullptr;
    short* Ch = nullptr;

    if (t < 384) {
        const int job = t >> 7, jt = t & 127;
        bm = (jt >> 3) * 64; bn = (jt & 7) * 128;
        lda = 1024; ldc = 1024;
        if (job == 0)      { Ap = ob16; Bp = w1t;         ldb = 1024; bias = w_b;   Cf = s_out;   }
        else if (job == 1) { Ap = cb16; Bp = w2t;         ldb = 1024;               Ch = s_ctx16; }
        else               { Ap = ob16; Bp = lint + 1024; ldb = 2048; bias = lin_b; Cf = outlin;  }
    } else {
        const int tt = t - 384, bz = tt >> 4, tw = tt & 15;
        bm = tw * 64; bn = 0;
        Ap = lint; lda = 2048;
        Bp = cb16 + (long)bz * (kI * kD); ldb = 1024;
        Ch = ctxlin + (long)bz * (kD * kI); ldc = 128;
    }

    const int m0 = (w >> 1) * 32, n0 = (w & 1) * 64;
    const int fr = lane & 15, fcol = lane >> 4, sl = lane & 7;
    const int r8 = lane >> 3;
    const int sw8 = ((lane & 7) ^ r8) * 8;   // swizzled source col (shorts)
    const int w16 = w * 16, w32 = w * 32;

    f32x4 acc[2][4] = {};

    auto stage = [&](int buf, int k0) {
        const short* ga = Ap + (long)(bm + w16 + r8) * lda + k0 + sw8;
        gll16(ga,                 &As[buf][w16][0]);
        gll16(ga + 8 * (long)lda, &As[buf][w16 + 8][0]);
        const short* gb = Bp + (long)(bn + w32 + r8) * ldb + k0 + sw8;
        gll16(gb,                  &Bs[buf][w32][0]);
        gll16(gb + 8 * (long)ldb,  &Bs[buf][w32 + 8][0]);
        gll16(gb + 16 * (long)ldb, &Bs[buf][w32 + 16][0]);
        gll16(gb + 24 * (long)ldb, &Bs[buf][w32 + 24][0]);
    };

    stage(0, 0);
    __syncthreads();
    int cur = 0;
    for (int s = 0; s < 16; ++s) {
        if (s < 15) stage(cur ^ 1, (s + 1) << 6);
#pragma unroll
        for (int ks8 = 0; ks8 < 8; ks8 += 4) {      // ks = 0, 32
            const int sa = ((ks8 + fcol) ^ sl) * 8; // swizzled read col (shorts)
            short8 a[2], b[4];
#pragma unroll
            for (int mi = 0; mi < 2; ++mi)
                a[mi] = *(const short8*)&As[cur][m0 + mi * 16 + fr][sa];
#pragma unroll
            for (int ni = 0; ni < 4; ++ni)
                b[ni] = *(const short8*)&Bs[cur][n0 + ni * 16 + fr][sa];
#pragma unroll
            for (int mi = 0; mi < 2; ++mi)
#pragma unroll
                for (int ni = 0; ni < 4; ++ni)
                    acc[mi][ni] = __builtin_amdgcn_mfma_f32_16x16x32_bf16(
                        a[mi], b[ni], acc[mi][ni], 0, 0, 0);
        }
        __syncthreads();
        cur ^= 1;
    }

    float bv[4] = {0, 0, 0, 0};
    if (bias) {
#pragma unroll
        for (int ni = 0; ni < 4; ++ni) bv[ni] = bias[bn + n0 + ni * 16 + fr];
    }
#pragma unroll
    for (int mi = 0; mi < 2; ++mi)
#pragma unroll
        for (int ni = 0; ni < 4; ++ni)
#pragma unroll
            for (int r = 0; r < 4; ++r) {
                const int row = bm + m0 + mi * 16 + ((lane >> 4) << 2) + r;
                const int col = bn + n0 + ni * 16 + fr;
                float v = acc[mi][ni][r] + bv[ni];
                if (Ch) Ch[(long)row * ldc + col] = f2bf(v);
                else    Cf[(long)row * ldc + col] = v;
            }
}

// ---------------------------------------------------------------------------
// Fused score + mask + softmax + final GEMM, v2.
// Grid (8, 64) = 512 blocks (o-PAIRS) -> 2 blocks/CU (LDS ~55KB).
// Score: leaky(x)=0.505x+0.495|x|; 4 waves = 4 d-quarters; s_ctx bf16 chunks
// double-buffered via swizzled gll16 (CsPool 32KB). Partials via LDS.
// Final: out[b,o0+r,:] = leaky(P @ ctxlin[b]^T + outlin), P padded 2->16 rows,
// B staged 64 n-rows/step dbuf in the SAME 32KB pool, 16 steps, 4 MFMA/wave.
// ---------------------------------------------------------------------------
__global__ __launch_bounds__(256)
void score_final(const float* __restrict__ s_out, const short* __restrict__ s_ctx16,
                 const float* __restrict__ score_w, const float* __restrict__ score_b,
                 const int* __restrict__ mask, const short* __restrict__ ctxlin,
                 const float* __restrict__ outlin, float* __restrict__ out_main,
                 float* __restrict__ attn_f32)
{
    __shared__ float As[2][1032];                   // 2 o-rows fp32 (8.25KB)
    __shared__ __align__(16) char CsPool[32768];    // score Cs dbuf / final B dbuf
    __shared__ float Wsh[1024];                     // 4KB
    __shared__ float Ps[4][2][128];                 // sa partials (4KB)
    __shared__ float Psi[4][128];                   // si partials (2KB)
    __shared__ float so_sh[2];
    __shared__ int   Msk[128];
    __shared__ __align__(16) short Pl[16][136];     // P rows padded to 16 (4.25KB)

    short* CsS = (short*)CsPool;                    // [2][128][64] bf16
    const int b   = blockIdx.x;
    const int o0  = blockIdx.y * 2;
    const int tid = threadIdx.x;
    const int wv  = tid >> 6;          // d-quarter (wave-uniform)
    const int ln  = tid & 63;          // i low half; also owns i+64
    const int fr  = ln & 15, fg = ln >> 4;

    // ---- prologue: stage As (fp32), Wsh, Msk; zero Pl ----
    const float* arow = s_out + (long)(b * kO + o0) * kD;
#pragma unroll
    for (int q = 0; q < 2; ++q) {      // 2 rows x 1024 = 512 float4
        const int tq = tid + q * 256;
        const int rr = tq >> 8, c4 = (tq & 255) * 4;
        *(float4*)&As[rr][c4] = *(const float4*)&arow[(long)rr * kD + c4];
    }
    *(float4*)&Wsh[tid * 4] = *(const float4*)&score_w[tid * 4];
    if (tid < 128) Msk[tid] = mask[b * kI + tid];
    {
        short* pf = &Pl[0][0];                      // 16*136 = 2176 shorts = 272 x 16B
        for (int j = tid; j < 272; j += 256) *(short8*)(pf + j * 8) = short8{};
    }

    const short* crow = s_ctx16 + (long)b * kI * kD;
    auto stageCs = [&](int buf, int dc) {
#pragma unroll
        for (int it = 0; it < 4; ++it) {
            const int rb = wv * 32 + it * 8;        // dest row base (8 rows/call)
            const int r  = rb + (ln >> 3);
            const int sc = (ln & 7) ^ (r & 7);      // swizzled source chunk
            gll16(crow + (long)r * kD + dc + sc * 8, CsS + buf * 8192 + rb * 64);
        }
    };

    stageCs(0, 0);
    __syncthreads();

    // ---- so[o] = sum_d s_out[o,d]*w[d]; waves 0,1 ----
    if (wv < 2) {
        float acc = 0.0f;
#pragma unroll
        for (int j = 0; j < 16; j += 4) {
            const float4 av = *(const float4*)&As[wv][ln * 16 + j];
            const float4 ww = *(const float4*)&Wsh[ln * 16 + j];
            acc = fmaf(av.x, ww.x, acc); acc = fmaf(av.y, ww.y, acc);
            acc = fmaf(av.z, ww.z, acc); acc = fmaf(av.w, ww.w, acc);
        }
#pragma unroll
        for (int d = 1; d < 64; d <<= 1) acc += __shfl_xor(acc, d, 64);
        if (ln == 0) so_sh[wv] = acc;
    }

    // ---- main loop: sa = sum |av+c|*w  (per o), si = sum c*w ----
    float sa0[2] = {}, sa1[2] = {};
    float si0 = 0.0f, si1 = 0.0f;
    const int kb = wv * 16;            // this wave's d-slice within each chunk

    int buf = 0;
    for (int c = 0; c < 16; ++c) {
        const int dc = c * 64;
        if (c < 15) stageCs(buf ^ 1, dc + 64);
        const int sc0 = ((wv * 2 + 0) ^ (ln & 7)) * 8;
        const int sc1 = ((wv * 2 + 1) ^ (ln & 7)) * 8;
        const short8 cA0 = *(const short8*)&CsS[buf * 8192 + ln * 64 + sc0];
        const short8 cA1 = *(const short8*)&CsS[buf * 8192 + ln * 64 + sc1];
        const short8 cB0 = *(const short8*)&CsS[buf * 8192 + (ln + 64) * 64 + sc0];
        const short8 cB1 = *(const short8*)&CsS[buf * 8192 + (ln + 64) * 64 + sc1];
        float c0[16], c1[16];
        b8tof(cA0, c0); b8tof(cA1, c0 + 8);
        b8tof(cB0, c1); b8tof(cB1, c1 + 8);
        float wr[16], av[2][16];
#pragma unroll
        for (int q = 0; q < 4; ++q) {
            *(float4*)&wr[q * 4]    = *(const float4*)&Wsh[dc + kb + q * 4];
            *(float4*)&av[0][q * 4] = *(const float4*)&As[0][dc + kb + q * 4];
            *(float4*)&av[1][q * 4] = *(const float4*)&As[1][dc + kb + q * 4];
        }
#pragma unroll
        for (int d = 0; d < 16; ++d) {
            si0 = fmaf(c0[d], wr[d], si0);
            si1 = fmaf(c1[d], wr[d], si1);
#pragma unroll
            for (int o = 0; o < 2; ++o) {
                sa0[o] = fmaf(__builtin_fabsf(av[o][d] + c0[d]), wr[d], sa0[o]);
                sa1[o] = fmaf(__builtin_fabsf(av[o][d] + c1[d]), wr[d], sa1[o]);
            }
        }
        __syncthreads();               // drains gll16 vmcnt + protects Cs
        buf ^= 1;
    }

    // ---- start staging final-GEMM B block 0 (overlaps partial-combine) ----
    short* Bsh = (short*)CsPool;                    // [2][64][128] bf16
    const short* ctxb = ctxlin + (long)b * (kD * kI);
    auto stageB = [&](int half, int nc) {
#pragma unroll
        for (int it = 0; it < 4; ++it) {
            const int rb = wv * 16 + it * 4;        // dest row base (4 rows/call)
            const int r  = rb + (ln >> 4);
            const int n  = nc * 64 + r;
            const int sc = (ln & 15) ^ (r & 7);     // swizzled source chunk
            gll16(ctxb + (long)n * kI + sc * 8, Bsh + half * 8192 + rb * kI);
        }
    };
    stageB(0, 0);                                   // writes Cs[0] region: dead

#pragma unroll
    for (int o = 0; o < 2; ++o) {
        Ps[wv][o][ln]      = (o == 0) ? sa0[0] : sa0[1];
        Ps[wv][o][ln + 64] = (o == 0) ? sa1[0] : sa1[1];
    }
    Psi[wv][ln]      = si0;
    Psi[wv][ln + 64] = si1;
    __syncthreads();

    // ---- combine + mask + softmax; waves 0,1 handle o-rows 0,1 ----
    if (wv < 2) {
        const int ow = wv;
        const float negInf = -__builtin_huge_valf();
        const float sb = score_b[0];
        const float siT0 = Psi[0][ln] + Psi[1][ln] + Psi[2][ln] + Psi[3][ln];
        const float siT1 = Psi[0][ln + 64] + Psi[1][ln + 64]
                         + Psi[2][ln + 64] + Psi[3][ln + 64];
        const float saT0 = Ps[0][ow][ln] + Ps[1][ow][ln]
                         + Ps[2][ow][ln] + Ps[3][ow][ln];
        const float saT1 = Ps[0][ow][ln + 64] + Ps[1][ow][ln + 64]
                         + Ps[2][ow][ln + 64] + Ps[3][ow][ln + 64];
        const float soV = so_sh[ow];
        float s0 = 0.505f * (soV + siT0) + 0.495f * saT0 + sb;
        float s1 = 0.505f * (soV + siT1) + 0.495f * saT1 + sb;
        if (Msk[ln]      != 0) s0 = negInf;
        if (Msk[ln + 64] != 0) s1 = negInf;

        float m = fmaxf(s0, s1);
#pragma unroll
        for (int d = 1; d < 64; d <<= 1) m = fmaxf(m, __shfl_xor(m, d, 64));
        const float e0 = __expf(s0 - m);
        const float e1 = __expf(s1 - m);
        float sum = e0 + e1;
#pragma unroll
        for (int d = 1; d < 64; d <<= 1) sum += __shfl_xor(sum, d, 64);
        const float inv = 1.0f / sum;

        const long rowoff = (long)(b * kO + o0 + ow) * kI;
        const float p0 = e0 * inv, p1 = e1 * inv;
        attn_f32[rowoff + ln]      = p0;
        attn_f32[rowoff + ln + 64] = p1;
        Pl[ow][ln]      = f2bf(p0);
        Pl[ow][ln + 64] = f2bf(p1);
    }
    __syncthreads();                   // Pl visible; Bsh half0 complete

    // ---- final GEMM: 16 steps of 64 n-rows, dbuf; 4 MFMA/wave/step ----
    int half = 0;
    for (int nc = 0; nc < 16; ++nc) {
        if (nc < 15) stageB(half ^ 1, nc + 1);
        const short* Bc = Bsh + half * 8192;
        f32x4 acc{};
#pragma unroll
        for (int ks = 0; ks < 4; ++ks) {
            const short8 a = *(const short8*)&Pl[fr][ks * 32 + fg * 8];
            const int sc = ((ks * 4 + fg) ^ (fr & 7)) * 8;
            const short8 bb = *(const short8*)&Bc[(wv * 16 + fr) * kI + sc];
            acc = __builtin_amdgcn_mfma_f32_16x16x32_bf16(a, bb, acc, 0, 0, 0);
        }
        if (fg == 0) {                 // real P-rows are m = 0,1 (fg*4 + r)
#pragma unroll
            for (int r = 0; r < 2; ++r) {
                const int n = nc * 64 + wv * 16 + fr;
                const long off = (long)(b * kO + o0 + r) * kD + n;
                out_main[off] = leaky(acc[r] + outlin[off]);
            }
        }
        __syncthreads();
        half ^= 1;
    }
}

} // namespace

extern "C" void kernel_launch(void* const* d_in, const int* in_sizes, int n_in,
                              void* d_out, int out_size, void* d_ws, size_t ws_size,
                              hipStream_t stream)
{
    const float* output  = (const float*)d_in[0];   // [B,O,D]
    const float* context = (const float*)d_in[1];   // [B,I,D]
    const int*   mask    = (const int*)d_in[2];     // [B,I]
    const float* w_out_w = (const float*)d_in[3];   // [D,D]
    const float* w_ctx_w = (const float*)d_in[4];   // [D,D]
    const float* w_b     = (const float*)d_in[5];   // [D]
    const float* score_w = (const float*)d_in[6];   // [D]
    const float* score_b = (const float*)d_in[7];   // scalar
    const float* lin_w   = (const float*)d_in[8];   // [2D,D]
    const float* lin_b   = (const float*)d_in[9];   // [D]

    float* out_main = (float*)d_out;                 // [B,O,D]
    float* out_attn = out_main + kOutAttnOff;        // [B,O,I]
    float* s_out    = out_main;                      // overlay: block reads its 2
                                                     // rows before rewriting them

    char* wp = (char*)d_ws;
    short* s_ctx16 = (short*)wp;  wp += (size_t)2 << 20;  // s_ctx bf16 [B*I][D]
    short* ob16    = (short*)wp;  wp += (size_t)2 << 20;  // output bf16
    short* cb16    = (short*)wp;  wp += (size_t)2 << 20;  // context bf16
    short* w1t     = (short*)wp;  wp += (size_t)2 << 20;  // w_out_w^T bf16
    short* w2t     = (short*)wp;  wp += (size_t)2 << 20;  // w_ctx_w^T bf16
    short* lint    = (short*)wp;  wp += (size_t)4 << 20;  // lin_w^T bf16 [1024][2048]
    float* outlin  = (float*)wp;  wp += (size_t)4 << 20;  // output@lin_bot+lin_b fp32
    short* ctxlin  = (short*)wp;                          // (ctx@lin_top)^T bf16 [b][1024][128]

    const dim3 blk(256);

    // 1) all conversions
    hipLaunchKernelGGL(conv_all, dim3(2048), blk, 0, stream,
        output, context, w_out_w, w_ctx_w, lin_w, ob16, cb16, w1t, w2t, lint);

    // 2) all input-independent GEMMs in one 512-block launch
    hipLaunchKernelGGL(mm_jobs, dim3(512), blk, 0, stream,
        ob16, cb16, w1t, w2t, lint, w_b, lin_b, s_out, s_ctx16, outlin, ctxlin);

    // 3) score + softmax + final GEMM fused (512 blocks, 2/CU)
    hipLaunchKernelGGL(score_final, dim3(8, 64), blk, 0, stream,
        s_out, s_ctx16, score_w, score_b, mask, ctxlin, outlin, out_main, out_attn);
}

// Round 9
// 64.431 us; speedup vs baseline: 3.7775x; 1.0021x over previous
//
#include <hip/hip_runtime.h>

namespace {

constexpr int kB = 8, kO = 128, kI = 128, kD = 1024;
constexpr long kOutAttnOff = (long)kB * kO * kD;   // 1,048,576 floats

typedef __attribute__((ext_vector_type(8))) short short8;  // 8 bf16 = 4 VGPR
typedef __attribute__((ext_vector_type(4))) float f32x4;

__device__ __forceinline__ float leaky(float x) { return fmaxf(x, 0.01f * x); }

// fp32 -> bf16 round-to-nearest-even
__device__ __forceinline__ short f2bf(float f) {
    unsigned u = __builtin_bit_cast(unsigned, f);
    u += 0x7FFFu + ((u >> 16) & 1u);
    return (short)(u >> 16);
}

// short8 of bf16 -> 8 f32 (1 op per value: shl / and)
__device__ __forceinline__ void b8tof(const short8 v, float* f) {
    const unsigned* u = (const unsigned*)&v;
#pragma unroll
    for (int j = 0; j < 4; ++j) {
        f[2 * j]     = __builtin_bit_cast(float, u[j] << 16);
        f[2 * j + 1] = __builtin_bit_cast(float, u[j] & 0xffff0000u);
    }
}

// async global->LDS, 16B per lane. LDS dest = wave-uniform base + lane*16.
__device__ __forceinline__ void gll16(const void* g, void* l) {
    __builtin_amdgcn_global_load_lds(
        (const __attribute__((address_space(1))) int*)g,
        (__attribute__((address_space(3))) int*)l, 16, 0, 0);
}

#define VMWAIT4() asm volatile("s_waitcnt vmcnt(4)" ::: "memory")
#define VMWAIT6() asm volatile("s_waitcnt vmcnt(6)" ::: "memory")
#define VMWAIT0() asm volatile("s_waitcnt vmcnt(0)" ::: "memory")
#define LGKM0()   asm volatile("s_waitcnt lgkmcnt(0)" ::: "memory")
#define BAR()     __builtin_amdgcn_s_barrier()

// ---------------------------------------------------------------------------
// All input conversions in ONE kernel (unchanged from round 5/7/8).
// ---------------------------------------------------------------------------
__global__ __launch_bounds__(256)
void conv_all(const float* __restrict__ output, const float* __restrict__ context,
              const float* __restrict__ w1, const float* __restrict__ w2,
              const float* __restrict__ lin,
              short* __restrict__ ob16, short* __restrict__ cb16,
              short* __restrict__ w1t, short* __restrict__ w2t,
              short* __restrict__ lint)
{
    __shared__ float T[64][68];
    const int bid = blockIdx.x, tid = threadIdx.x;

    if (bid < 1024) {                       // straight convert, 8 floats/thread
        const int idx = bid * 256 + tid;
        const float* src; short* dst; int i;
        if (idx < (1 << 17)) { src = output;  dst = ob16; i = idx; }
        else                 { src = context; dst = cb16; i = idx - (1 << 17); }
        const float4* s4 = (const float4*)src + (long)i * 2;
        const float4 v0 = s4[0], v1 = s4[1];
        short8 r;
        r[0] = f2bf(v0.x); r[1] = f2bf(v0.y); r[2] = f2bf(v0.z); r[3] = f2bf(v0.w);
        r[4] = f2bf(v1.x); r[5] = f2bf(v1.y); r[6] = f2bf(v1.z); r[7] = f2bf(v1.w);
        *(short8*)(dst + (long)i * 8) = r;
        return;
    }

    const int tb = bid - 1024;
    const float* src; short* dst; long C, R; int t2;
    if (tb < 256)      { src = w1;  dst = w1t;  R = 1024; C = 1024; t2 = tb; }
    else if (tb < 512) { src = w2;  dst = w2t;  R = 1024; C = 1024; t2 = tb - 256; }
    else               { src = lin; dst = lint; R = 2048; C = 1024; t2 = tb - 512; }
    const int tr = t2 >> 4, tc = t2 & 15;
    const int r = tid >> 2, q = tid & 3;

    const float* s = src + (long)(tr * 64 + r) * C + tc * 64 + q * 16;
    const float4 a0 = ((const float4*)s)[0];
    const float4 a1 = ((const float4*)s)[1];
    const float4 a2 = ((const float4*)s)[2];
    const float4 a3 = ((const float4*)s)[3];
    *(float4*)&T[r][q * 16 + 0]  = a0;
    *(float4*)&T[r][q * 16 + 4]  = a1;
    *(float4*)&T[r][q * 16 + 8]  = a2;
    *(float4*)&T[r][q * 16 + 12] = a3;
    __syncthreads();

    short8 o0, o1;
#pragma unroll
    for (int j = 0; j < 8; ++j)  o0[j] = f2bf(T[q * 16 + j][r]);
#pragma unroll
    for (int j = 0; j < 8; ++j)  o1[j] = f2bf(T[q * 16 + 8 + j][r]);
    short* dp = dst + (long)(tc * 64 + r) * R + tr * 64 + q * 16;
    *(short8*)dp       = o0;
    *((short8*)dp + 1) = o1;
}

// ---------------------------------------------------------------------------
// Fused independent-GEMM job table, 512 blocks. Now TRIPLE-buffered LDS with
// counted vmcnt + raw s_barrier (T4): loads for step s+2 stay in flight
// across the barrier; the wait only drains step s+1 (2 chunks old).
// ---------------------------------------------------------------------------
__global__ __launch_bounds__(256)
void mm_jobs(const short* __restrict__ ob16, const short* __restrict__ cb16,
             const short* __restrict__ w1t, const short* __restrict__ w2t,
             const short* __restrict__ lint,
             const float* __restrict__ w_b, const float* __restrict__ lin_b,
             float* __restrict__ s_out, short* __restrict__ s_ctx16,
             float* __restrict__ outlin, short* __restrict__ ctxlin)
{
    __shared__ short As[3][64][64];    // 24KB
    __shared__ short Bs[3][128][64];   // 48KB
    const int tid = threadIdx.x;
    const int t = blockIdx.x;
    const int lane = tid & 63, w = tid >> 6;

    const short *Ap, *Bp;
    int lda, ldb, bm, bn, ldc;
    const float* bias = nullptr;
    float* Cf = nullptr;
    short* Ch = nullptr;

    if (t < 384) {
        const int job = t >> 7, jt = t & 127;
        bm = (jt >> 3) * 64; bn = (jt & 7) * 128;
        lda = 1024; ldc = 1024;
        if (job == 0)      { Ap = ob16; Bp = w1t;         ldb = 1024; bias = w_b;   Cf = s_out;   }
        else if (job == 1) { Ap = cb16; Bp = w2t;         ldb = 1024;               Ch = s_ctx16; }
        else               { Ap = ob16; Bp = lint + 1024; ldb = 2048; bias = lin_b; Cf = outlin;  }
    } else {
        const int tt = t - 384, bz = tt >> 4, tw = tt & 15;
        bm = tw * 64; bn = 0;
        Ap = lint; lda = 2048;
        Bp = cb16 + (long)bz * (kI * kD); ldb = 1024;
        Ch = ctxlin + (long)bz * (kD * kI); ldc = 128;
    }

    const int m0 = (w >> 1) * 32, n0 = (w & 1) * 64;
    const int fr = lane & 15, fcol = lane >> 4, sl = lane & 7;
    const int r8 = lane >> 3;
    const int sw8 = ((lane & 7) ^ r8) * 8;   // swizzled source col (shorts)
    const int w16 = w * 16, w32 = w * 32;

    f32x4 acc[2][4] = {};

    auto stage = [&](int buf, int k0) {      // 6 gll16 per wave
        const short* ga = Ap + (long)(bm + w16 + r8) * lda + k0 + sw8;
        gll16(ga,                 &As[buf][w16][0]);
        gll16(ga + 8 * (long)lda, &As[buf][w16 + 8][0]);
        const short* gb = Bp + (long)(bn + w32 + r8) * ldb + k0 + sw8;
        gll16(gb,                  &Bs[buf][w32][0]);
        gll16(gb + 8 * (long)ldb,  &Bs[buf][w32 + 8][0]);
        gll16(gb + 16 * (long)ldb, &Bs[buf][w32 + 16][0]);
        gll16(gb + 24 * (long)ldb, &Bs[buf][w32 + 24][0]);
    };

    stage(0, 0);
    stage(1, 64);
    VMWAIT6();                               // slot0 complete; slot1 in flight
    BAR();

    int cur = 0, s2 = 2;
    for (int s = 0; s < 16; ++s) {
        if (s + 2 < 16) stage(s2, (s + 2) << 6);
#pragma unroll
        for (int ks8 = 0; ks8 < 8; ks8 += 4) {      // ks = 0, 32
            const int sa = ((ks8 + fcol) ^ sl) * 8; // swizzled read col (shorts)
            short8 a[2], b[4];
#pragma unroll
            for (int mi = 0; mi < 2; ++mi)
                a[mi] = *(const short8*)&As[cur][m0 + mi * 16 + fr][sa];
#pragma unroll
            for (int ni = 0; ni < 4; ++ni)
                b[ni] = *(const short8*)&Bs[cur][n0 + ni * 16 + fr][sa];
#pragma unroll
            for (int mi = 0; mi < 2; ++mi)
#pragma unroll
                for (int ni = 0; ni < 4; ++ni)
                    acc[mi][ni] = __builtin_amdgcn_mfma_f32_16x16x32_bf16(
                        a[mi], b[ni], acc[mi][ni], 0, 0, 0);
        }
        if (s < 14)       VMWAIT6();         // next slot ready; s+2 in flight
        else if (s == 14) VMWAIT0();
        if (s < 15) BAR();
        cur = (cur == 2) ? 0 : cur + 1;
        s2  = (s2 == 2) ? 0 : s2 + 1;
    }

    float bv[4] = {0, 0, 0, 0};
    if (bias) {
#pragma unroll
        for (int ni = 0; ni < 4; ++ni) bv[ni] = bias[bn + n0 + ni * 16 + fr];
    }
#pragma unroll
    for (int mi = 0; mi < 2; ++mi)
#pragma unroll
        for (int ni = 0; ni < 4; ++ni)
#pragma unroll
            for (int r = 0; r < 4; ++r) {
                const int row = bm + m0 + mi * 16 + ((lane >> 4) << 2) + r;
                const int col = bn + n0 + ni * 16 + fr;
                float v = acc[mi][ni][r] + bv[ni];
                if (Ch) Ch[(long)row * ldc + col] = f2bf(v);
                else    Cf[(long)row * ldc + col] = v;
            }
}

// ---------------------------------------------------------------------------
// Fused score + mask + softmax + final GEMM, v3: triple-buffered staging with
// counted vmcnt + raw s_barrier in BOTH loops; B-staging for the final GEMM
// issued before softmax so its latency hides under it.
// Grid (8, 64) = 512 blocks (o-pairs), 4 waves, LDS ~71KB -> 2 blocks/CU.
// ---------------------------------------------------------------------------
__global__ __launch_bounds__(256)
void score_final(const float* __restrict__ s_out, const short* __restrict__ s_ctx16,
                 const float* __restrict__ score_w, const float* __restrict__ score_b,
                 const int* __restrict__ mask, const short* __restrict__ ctxlin,
                 const float* __restrict__ outlin, float* __restrict__ out_main,
                 float* __restrict__ attn_f32)
{
    __shared__ float As[2][1032];                   // 2 o-rows fp32 (8.25KB)
    __shared__ __align__(16) char CsPool[49152];    // 3 x 16KB slots (Cs / B)
    __shared__ float Wsh[1024];                     // 4KB
    __shared__ float Ps[4][2][128];                 // sa partials (4KB)
    __shared__ float Psi[4][128];                   // si partials (2KB)
    __shared__ float so_sh[2];
    __shared__ int   Msk[128];
    __shared__ __align__(16) short Pl[16][136];     // P rows padded to 16 (4.25KB)

    short* CsS = (short*)CsPool;                    // slot s: CsS + s*8192 shorts
    const int b   = blockIdx.x;
    const int o0  = blockIdx.y * 2;
    const int tid = threadIdx.x;
    const int wv  = tid >> 6;          // d-quarter (wave-uniform)
    const int ln  = tid & 63;          // i low half; also owns i+64
    const int fr  = ln & 15, fg = ln >> 4;

    const short* crow = s_ctx16 + (long)b * kI * kD;
    auto stageCs = [&](int slot, int dc) {          // 4 gll16 per wave
#pragma unroll
        for (int it = 0; it < 4; ++it) {
            const int rb = wv * 32 + it * 8;        // dest row base (8 rows/call)
            const int r  = rb + (ln >> 3);
            const int sc = (ln & 7) ^ (r & 7);      // swizzled source chunk
            gll16(crow + (long)r * kD + dc + sc * 8, CsS + slot * 8192 + rb * 64);
        }
    };

    stageCs(0, 0);                                  // in flight under prologue
    stageCs(1, 64);

    // ---- prologue: stage As (fp32), Wsh, Msk; zero Pl ----
    const float* arow = s_out + (long)(b * kO + o0) * kD;
#pragma unroll
    for (int q = 0; q < 2; ++q) {      // 2 rows x 1024 = 512 float4
        const int tq = tid + q * 256;
        const int rr = tq >> 8, c4 = (tq & 255) * 4;
        *(float4*)&As[rr][c4] = *(const float4*)&arow[(long)rr * kD + c4];
    }
    *(float4*)&Wsh[tid * 4] = *(const float4*)&score_w[tid * 4];
    if (tid < 128) Msk[tid] = mask[b * kI + tid];
    {
        short* pf = &Pl[0][0];                      // 16*136 = 2176 shorts
        for (int j = tid; j < 272; j += 256) *(short8*)(pf + j * 8) = short8{};
    }

    VMWAIT4();                          // slot0 done (newest 4 = slot1)
    LGKM0();
    BAR();

    // ---- so[o] = sum_d s_out[o,d]*w[d]; waves 0,1 ----
    if (wv < 2) {
        float acc = 0.0f;
#pragma unroll
        for (int j = 0; j < 16; j += 4) {
            const float4 av = *(const float4*)&As[wv][ln * 16 + j];
            const float4 ww = *(const float4*)&Wsh[ln * 16 + j];
            acc = fmaf(av.x, ww.x, acc); acc = fmaf(av.y, ww.y, acc);
            acc = fmaf(av.z, ww.z, acc); acc = fmaf(av.w, ww.w, acc);
        }
#pragma unroll
        for (int d = 1; d < 64; d <<= 1) acc += __shfl_xor(acc, d, 64);
        if (ln == 0) so_sh[wv] = acc;
    }

    // ---- main loop: sa = sum |av+c|*w  (per o), si = sum c*w ----
    float sa0[2] = {}, sa1[2] = {};
    float si0 = 0.0f, si1 = 0.0f;
    const int kb = wv * 16;            // this wave's d-slice within each chunk

    int buf = 0, s2 = 2;
    for (int c = 0; c < 16; ++c) {
        if (c + 2 < 16) stageCs(s2, (c + 2) * 64);
        const int dc = c * 64;
        const short* Cb = CsS + buf * 8192;
        const int sc0 = ((wv * 2 + 0) ^ (ln & 7)) * 8;
        const int sc1 = ((wv * 2 + 1) ^ (ln & 7)) * 8;
        const short8 cA0 = *(const short8*)&Cb[ln * 64 + sc0];
        const short8 cA1 = *(const short8*)&Cb[ln * 64 + sc1];
        const short8 cB0 = *(const short8*)&Cb[(ln + 64) * 64 + sc0];
        const short8 cB1 = *(const short8*)&Cb[(ln + 64) * 64 + sc1];
        float c0[16], c1[16];
        b8tof(cA0, c0); b8tof(cA1, c0 + 8);
        b8tof(cB0, c1); b8tof(cB1, c1 + 8);
        float wr[16], av[2][16];
#pragma unroll
        for (int q = 0; q < 4; ++q) {
            *(float4*)&wr[q * 4]    = *(const float4*)&Wsh[dc + kb + q * 4];
            *(float4*)&av[0][q * 4] = *(const float4*)&As[0][dc + kb + q * 4];
            *(float4*)&av[1][q * 4] = *(const float4*)&As[1][dc + kb + q * 4];
        }
#pragma unroll
        for (int d = 0; d < 16; ++d) {
            si0 = fmaf(c0[d], wr[d], si0);
            si1 = fmaf(c1[d], wr[d], si1);
#pragma unroll
            for (int o = 0; o < 2; ++o) {
                sa0[o] = fmaf(__builtin_fabsf(av[o][d] + c0[d]), wr[d], sa0[o]);
                sa1[o] = fmaf(__builtin_fabsf(av[o][d] + c1[d]), wr[d], sa1[o]);
            }
        }
        if (c < 14)       VMWAIT4();    // chunk c+1 landed; c+2 in flight
        else if (c == 14) VMWAIT0();
        BAR();                          // c==15: protects slot reuse by stageB
        buf = (buf == 2) ? 0 : buf + 1;
        s2  = (s2 == 2) ? 0 : s2 + 1;
    }

    // ---- stage final-GEMM B slots 0,1 (hide under partials + softmax) ----
    short* Bsh = (short*)CsPool;                    // slot h: Bsh + h*8192
    const short* ctxb = ctxlin + (long)b * (kD * kI);
    auto stageB = [&](int slot, int nc) {           // 4 gll16 per wave
#pragma unroll
        for (int it = 0; it < 4; ++it) {
            const int rb = wv * 16 + it * 4;        // dest row base (4 rows/call)
            const int r  = rb + (ln >> 4);
            const int n  = nc * 64 + r;
            const int sc = (ln & 15) ^ (r & 7);     // swizzled source chunk
            gll16(ctxb + (long)n * kI + sc * 8, Bsh + slot * 8192 + rb * kI);
        }
    };
    stageB(0, 0);
    stageB(1, 1);

#pragma unroll
    for (int o = 0; o < 2; ++o) {
        Ps[wv][o][ln]      = (o == 0) ? sa0[0] : sa0[1];
        Ps[wv][o][ln + 64] = (o == 0) ? sa1[0] : sa1[1];
    }
    Psi[wv][ln]      = si0;
    Psi[wv][ln + 64] = si1;
    LGKM0();
    BAR();                              // partials visible; B loads in flight

    // ---- combine + mask + softmax; waves 0,1 handle o-rows 0,1 ----
    if (wv < 2) {
        const int ow = wv;
        const float negInf = -__builtin_huge_valf();
        const float sb = score_b[0];
        const float siT0 = Psi[0][ln] + Psi[1][ln] + Psi[2][ln] + Psi[3][ln];
        const float siT1 = Psi[0][ln + 64] + Psi[1][ln + 64]
                         + Psi[2][ln + 64] + Psi[3][ln + 64];
        const float saT0 = Ps[0][ow][ln] + Ps[1][ow][ln]
                         + Ps[2][ow][ln] + Ps[3][ow][ln];
        const float saT1 = Ps[0][ow][ln + 64] + Ps[1][ow][ln + 64]
                         + Ps[2][ow][ln + 64] + Ps[3][ow][ln + 64];
        const float soV = so_sh[ow];
        float s0 = 0.505f * (soV + siT0) + 0.495f * saT0 + sb;
        float s1 = 0.505f * (soV + siT1) + 0.495f * saT1 + sb;
        if (Msk[ln]      != 0) s0 = negInf;
        if (Msk[ln + 64] != 0) s1 = negInf;

        float m = fmaxf(s0, s1);
#pragma unroll
        for (int d = 1; d < 64; d <<= 1) m = fmaxf(m, __shfl_xor(m, d, 64));
        const float e0 = __expf(s0 - m);
        const float e1 = __expf(s1 - m);
        float sum = e0 + e1;
#pragma unroll
        for (int d = 1; d < 64; d <<= 1) sum += __shfl_xor(sum, d, 64);
        const float inv = 1.0f / sum;

        const long rowoff = (long)(b * kO + o0 + ow) * kI;
        const float p0 = e0 * inv, p1 = e1 * inv;
        attn_f32[rowoff + ln]      = p0;
        attn_f32[rowoff + ln + 64] = p1;
        Pl[ow][ln]      = f2bf(p0);
        Pl[ow][ln + 64] = f2bf(p1);
    }
    VMWAIT4();                          // B slot0 done (newest 4 ~ slot1)
    LGKM0();                            // Pl visible
    BAR();

    // ---- final GEMM: 16 steps of 64 n-rows, triple-buffered ----
    int h = 0, h2 = 2;
    for (int nc = 0; nc < 16; ++nc) {
        if (nc + 2 < 16) stageB(h2, nc + 2);
        const short* Bc = Bsh + h * 8192;
        f32x4 acc{};
#pragma unroll
        for (int ks = 0; ks < 4; ++ks) {
            const short8 a = *(const short8*)&Pl[fr][ks * 32 + fg * 8];
            const int sc = ((ks * 4 + fg) ^ (fr & 7)) * 8;
            const short8 bb = *(const short8*)&Bc[(wv * 16 + fr) * kI + sc];
            acc = __builtin_amdgcn_mfma_f32_16x16x32_bf16(a, bb, acc, 0, 0, 0);
        }
        if (fg == 0) {                 // real P-rows are m = 0,1
#pragma unroll
            for (int r = 0; r < 2; ++r) {
                const int n = nc * 64 + wv * 16 + fr;
                const long off = (long)(b * kO + o0 + r) * kD + n;
                out_main[off] = leaky(acc[r] + outlin[off]);
            }
        }
        if (nc < 14)       VMWAIT4();
        else if (nc == 14) VMWAIT0();
        if (nc < 15) BAR();
        h  = (h == 2) ? 0 : h + 1;
        h2 = (h2 == 2) ? 0 : h2 + 1;
    }
}

} // namespace

extern "C" void kernel_launch(void* const* d_in, const int* in_sizes, int n_in,
                              void* d_out, int out_size, void* d_ws, size_t ws_size,
                              hipStream_t stream)
{
    const float* output  = (const float*)d_in[0];   // [B,O,D]
    const float* context = (const float*)d_in[1];   // [B,I,D]
    const int*   mask    = (const int*)d_in[2];     // [B,I]
    const float* w_out_w = (const float*)d_in[3];   // [D,D]
    const float* w_ctx_w = (const float*)d_in[4];   // [D,D]
    const float* w_b     = (const float*)d_in[5];   // [D]
    const float* score_w = (const float*)d_in[6];   // [D]
    const float* score_b = (const float*)d_in[7];   // scalar
    const float* lin_w   = (const float*)d_in[8];   // [2D,D]
    const float* lin_b   = (const float*)d_in[9];   // [D]

    float* out_main = (float*)d_out;                 // [B,O,D]
    float* out_attn = out_main + kOutAttnOff;        // [B,O,I]
    float* s_out    = out_main;                      // overlay: block reads its 2
                                                     // rows before rewriting them

    char* wp = (char*)d_ws;
    short* s_ctx16 = (short*)wp;  wp += (size_t)2 << 20;  // s_ctx bf16 [B*I][D]
    short* ob16    = (short*)wp;  wp += (size_t)2 << 20;  // output bf16
    short* cb16    = (short*)wp;  wp += (size_t)2 << 20;  // context bf16
    short* w1t     = (short*)wp;  wp += (size_t)2 << 20;  // w_out_w^T bf16
    short* w2t     = (short*)wp;  wp += (size_t)2 << 20;  // w_ctx_w^T bf16
    short* lint    = (short*)wp;  wp += (size_t)4 << 20;  // lin_w^T bf16 [1024][2048]
    float* outlin  = (float*)wp;  wp += (size_t)4 << 20;  // output@lin_bot+lin_b fp32
    short* ctxlin  = (short*)wp;                          // (ctx@lin_top)^T bf16 [b][1024][128]

    const dim3 blk(256);

    // 1) all conversions
    hipLaunchKernelGGL(conv_all, dim3(2048), blk, 0, stream,
        output, context, w_out_w, w_ctx_w, lin_w, ob16, cb16, w1t, w2t, lint);

    // 2) all input-independent GEMMs in one 512-block launch
    hipLaunchKernelGGL(mm_jobs, dim3(512), blk, 0, stream,
        ob16, cb16, w1t, w2t, lint, w_b, lin_b, s_out, s_ctx16, outlin, ctxlin);

    // 3) score + softmax + final GEMM fused (512 blocks, 2/CU)
    hipLaunchKernelGGL(score_final, dim3(8, 64), blk, 0, stream,
        s_out, s_ctx16, score_w, score_b, mask, ctxlin, outlin, out_main, out_attn);
}

// Round 10
// 63.393 us; speedup vs baseline: 3.8394x; 1.0164x over previous
//
#include <hip/hip_runtime.h>

namespace {

constexpr int kB = 8, kO = 128, kI = 128, kD = 1024;
constexpr long kOutAttnOff = (long)kB * kO * kD;   // 1,048,576 floats

typedef __attribute__((ext_vector_type(8))) short short8;  // 8 bf16 = 4 VGPR
typedef __attribute__((ext_vector_type(4))) float f32x4;
typedef __attribute__((ext_vector_type(2))) float f32x2;
typedef __attribute__((ext_vector_type(2))) unsigned u32x2;

__device__ __forceinline__ float leaky(float x) { return fmaxf(x, 0.01f * x); }

// fp32 -> bf16 round-to-nearest-even
__device__ __forceinline__ short f2bf(float f) {
    unsigned u = __builtin_bit_cast(unsigned, f);
    u += 0x7FFFu + ((u >> 16) & 1u);
    return (short)(u >> 16);
}
__device__ __forceinline__ float bf2f(short h) {
    return __builtin_bit_cast(float, ((unsigned)(unsigned short)h) << 16);
}
// short8 of bf16 -> 8 f32
__device__ __forceinline__ void b8tofs(const short8 v, float* f) {
    const unsigned* u = (const unsigned*)&v;
#pragma unroll
    for (int j = 0; j < 4; ++j) {
        f[2 * j]     = __builtin_bit_cast(float, u[j] << 16);
        f[2 * j + 1] = __builtin_bit_cast(float, u[j] & 0xffff0000u);
    }
}
// two short8 (same d-slice, rows i and i+64) -> f32x2 pairs {c_i, c_i64}
__device__ __forceinline__ void bpair(const short8 a, const short8 b, f32x2* p) {
    float fa[8], fb[8];
    b8tofs(a, fa); b8tofs(b, fb);
#pragma unroll
    for (int j = 0; j < 8; ++j) p[j] = f32x2{fa[j], fb[j]};
}
__device__ __forceinline__ f32x2 vabs2(f32x2 x) {
    u32x2 u = __builtin_bit_cast(u32x2, x);
    u &= 0x7fffffffu;
    return __builtin_bit_cast(f32x2, u);
}

// async global->LDS, 16B per lane. LDS dest = wave-uniform base + lane*16.
__device__ __forceinline__ void gll16(const void* g, void* l) {
    __builtin_amdgcn_global_load_lds(
        (const __attribute__((address_space(1))) int*)g,
        (__attribute__((address_space(3))) int*)l, 16, 0, 0);
}

// ---------------------------------------------------------------------------
// All input conversions in ONE kernel (unchanged).
// ---------------------------------------------------------------------------
__global__ __launch_bounds__(256)
void conv_all(const float* __restrict__ output, const float* __restrict__ context,
              const float* __restrict__ w1, const float* __restrict__ w2,
              const float* __restrict__ lin,
              short* __restrict__ ob16, short* __restrict__ cb16,
              short* __restrict__ w1t, short* __restrict__ w2t,
              short* __restrict__ lint)
{
    __shared__ float T[64][68];
    const int bid = blockIdx.x, tid = threadIdx.x;

    if (bid < 1024) {                       // straight convert, 8 floats/thread
        const int idx = bid * 256 + tid;
        const float* src; short* dst; int i;
        if (idx < (1 << 17)) { src = output;  dst = ob16; i = idx; }
        else                 { src = context; dst = cb16; i = idx - (1 << 17); }
        const float4* s4 = (const float4*)src + (long)i * 2;
        const float4 v0 = s4[0], v1 = s4[1];
        short8 r;
        r[0] = f2bf(v0.x); r[1] = f2bf(v0.y); r[2] = f2bf(v0.z); r[3] = f2bf(v0.w);
        r[4] = f2bf(v1.x); r[5] = f2bf(v1.y); r[6] = f2bf(v1.z); r[7] = f2bf(v1.w);
        *(short8*)(dst + (long)i * 8) = r;
        return;
    }

    const int tb = bid - 1024;
    const float* src; short* dst; long C, R; int t2;
    if (tb < 256)      { src = w1;  dst = w1t;  R = 1024; C = 1024; t2 = tb; }
    else if (tb < 512) { src = w2;  dst = w2t;  R = 1024; C = 1024; t2 = tb - 256; }
    else               { src = lin; dst = lint; R = 2048; C = 1024; t2 = tb - 512; }
    const int tr = t2 >> 4, tc = t2 & 15;
    const int r = tid >> 2, q = tid & 3;

    const float* s = src + (long)(tr * 64 + r) * C + tc * 64 + q * 16;
    const float4 a0 = ((const float4*)s)[0];
    const float4 a1 = ((const float4*)s)[1];
    const float4 a2 = ((const float4*)s)[2];
    const float4 a3 = ((const float4*)s)[3];
    *(float4*)&T[r][q * 16 + 0]  = a0;
    *(float4*)&T[r][q * 16 + 4]  = a1;
    *(float4*)&T[r][q * 16 + 8]  = a2;
    *(float4*)&T[r][q * 16 + 12] = a3;
    __syncthreads();

    short8 o0, o1;
#pragma unroll
    for (int j = 0; j < 8; ++j)  o0[j] = f2bf(T[q * 16 + j][r]);
#pragma unroll
    for (int j = 0; j < 8; ++j)  o1[j] = f2bf(T[q * 16 + 8 + j][r]);
    short* dp = dst + (long)(tc * 64 + r) * R + tr * 64 + q * 16;
    *(short8*)dp       = o0;
    *((short8*)dp + 1) = o1;
}

// ---------------------------------------------------------------------------
// Fused independent-GEMM job table, 512 blocks. R8 version: 2-slot LDS dbuf
// (48KB -> 3 blocks/CU), gll16 staging w/ XOR chunk swizzle, __syncthreads.
// ---------------------------------------------------------------------------
__global__ __launch_bounds__(256)
void mm_jobs(const short* __restrict__ ob16, const short* __restrict__ cb16,
             const short* __restrict__ w1t, const short* __restrict__ w2t,
             const short* __restrict__ lint,
             const float* __restrict__ w_b, const float* __restrict__ lin_b,
             float* __restrict__ s_out, short* __restrict__ s_ctx16,
             float* __restrict__ outlin, short* __restrict__ ctxlin)
{
    __shared__ short As[2][64][64];
    __shared__ short Bs[2][128][64];
    const int tid = threadIdx.x;
    const int t = blockIdx.x;
    const int lane = tid & 63, w = tid >> 6;

    const short *Ap, *Bp;
    int lda, ldb, bm, bn, ldc;
    const float* bias = nullptr;
    float* Cf = nullptr;
    short* Ch = nullptr;

    if (t < 384) {
        const int job = t >> 7, jt = t & 127;
        bm = (jt >> 3) * 64; bn = (jt & 7) * 128;
        lda = 1024; ldc = 1024;
        if (job == 0)      { Ap = ob16; Bp = w1t;         ldb = 1024; bias = w_b;   Cf = s_out;   }
        else if (job == 1) { Ap = cb16; Bp = w2t;         ldb = 1024;               Ch = s_ctx16; }
        else               { Ap = ob16; Bp = lint + 1024; ldb = 2048; bias = lin_b; Cf = outlin;  }
    } else {
        const int tt = t - 384, bz = tt >> 4, tw = tt & 15;
        bm = tw * 64; bn = 0;
        Ap = lint; lda = 2048;
        Bp = cb16 + (long)bz * (kI * kD); ldb = 1024;
        Ch = ctxlin + (long)bz * (kD * kI); ldc = 128;
    }

    const int m0 = (w >> 1) * 32, n0 = (w & 1) * 64;
    const int fr = lane & 15, fcol = lane >> 4, sl = lane & 7;
    const int r8 = lane >> 3;
    const int sw8 = ((lane & 7) ^ r8) * 8;   // swizzled source col (shorts)
    const int w16 = w * 16, w32 = w * 32;

    f32x4 acc[2][4] = {};

    auto stage = [&](int buf, int k0) {
        const short* ga = Ap + (long)(bm + w16 + r8) * lda + k0 + sw8;
        gll16(ga,                 &As[buf][w16][0]);
        gll16(ga + 8 * (long)lda, &As[buf][w16 + 8][0]);
        const short* gb = Bp + (long)(bn + w32 + r8) * ldb + k0 + sw8;
        gll16(gb,                  &Bs[buf][w32][0]);
        gll16(gb + 8 * (long)ldb,  &Bs[buf][w32 + 8][0]);
        gll16(gb + 16 * (long)ldb, &Bs[buf][w32 + 16][0]);
        gll16(gb + 24 * (long)ldb, &Bs[buf][w32 + 24][0]);
    };

    stage(0, 0);
    __syncthreads();
    int cur = 0;
    for (int s = 0; s < 16; ++s) {
        if (s < 15) stage(cur ^ 1, (s + 1) << 6);
#pragma unroll
        for (int ks8 = 0; ks8 < 8; ks8 += 4) {      // ks = 0, 32
            const int sa = ((ks8 + fcol) ^ sl) * 8; // swizzled read col (shorts)
            short8 a[2], b[4];
#pragma unroll
            for (int mi = 0; mi < 2; ++mi)
                a[mi] = *(const short8*)&As[cur][m0 + mi * 16 + fr][sa];
#pragma unroll
            for (int ni = 0; ni < 4; ++ni)
                b[ni] = *(const short8*)&Bs[cur][n0 + ni * 16 + fr][sa];
#pragma unroll
            for (int mi = 0; mi < 2; ++mi)
#pragma unroll
                for (int ni = 0; ni < 4; ++ni)
                    acc[mi][ni] = __builtin_amdgcn_mfma_f32_16x16x32_bf16(
                        a[mi], b[ni], acc[mi][ni], 0, 0, 0);
        }
        __syncthreads();
        cur ^= 1;
    }

    float bv[4] = {0, 0, 0, 0};
    if (bias) {
#pragma unroll
        for (int ni = 0; ni < 4; ++ni) bv[ni] = bias[bn + n0 + ni * 16 + fr];
    }
#pragma unroll
    for (int mi = 0; mi < 2; ++mi)
#pragma unroll
        for (int ni = 0; ni < 4; ++ni)
#pragma unroll
            for (int r = 0; r < 4; ++r) {
                const int row = bm + m0 + mi * 16 + ((lane >> 4) << 2) + r;
                const int col = bn + n0 + ni * 16 + fr;
                float v = acc[mi][ni][r] + bv[ni];
                if (Ch) Ch[(long)row * ldc + col] = f2bf(v);
                else    Cf[(long)row * ldc + col] = v;
            }
}

// ---------------------------------------------------------------------------
// Fused score + mask + softmax + final GEMM, v4.
// Grid (8, 64) = 512 blocks (o-pairs), 4 waves. LDS trimmed to ~52.8KB ->
// 3 blocks/CU (12 waves/CU, 3/SIMD): Cs 2-slot (32KB), Wsh bf16 (2KB),
// As fp32 (8.25KB). Inner loop packed f32x2 over (i, i+64).
// __launch_bounds__(256,3) caps VGPR at <=170 for the 3-wave/EU target.
// ---------------------------------------------------------------------------
__global__ __launch_bounds__(256, 3)
void score_final(const float* __restrict__ s_out, const short* __restrict__ s_ctx16,
                 const float* __restrict__ score_w, const float* __restrict__ score_b,
                 const int* __restrict__ mask, const short* __restrict__ ctxlin,
                 const float* __restrict__ outlin, float* __restrict__ out_main,
                 float* __restrict__ attn_f32)
{
    __shared__ float As[2][1032];                   // 2 o-rows fp32 (8.25KB)
    __shared__ __align__(16) char CsPool[32768];    // 2 x 16KB slots (Cs / B)
    __shared__ short Wsh[1032];                     // score_w bf16 (2KB)
    __shared__ float Ps[4][2][128];                 // sa partials (4KB)
    __shared__ float Psi[4][128];                   // si partials (2KB)
    __shared__ float so_sh[2];
    __shared__ int   Msk[128];
    __shared__ __align__(16) short Pl[16][136];     // P rows padded to 16 (4.25KB)

    short* CsS = (short*)CsPool;                    // slot s: CsS + s*8192 shorts
    const int b   = blockIdx.x;
    const int o0  = blockIdx.y * 2;
    const int tid = threadIdx.x;
    const int wv  = tid >> 6;          // d-quarter (wave-uniform)
    const int ln  = tid & 63;          // i low half; also owns i+64
    const int fr  = ln & 15, fg = ln >> 4;

    const short* crow = s_ctx16 + (long)b * kI * kD;
    auto stageCs = [&](int slot, int dc) {          // 4 gll16 per wave
#pragma unroll
        for (int it = 0; it < 4; ++it) {
            const int rb = wv * 32 + it * 8;        // dest row base (8 rows/call)
            const int r  = rb + (ln >> 3);
            const int sc = (ln & 7) ^ (r & 7);      // swizzled source chunk
            gll16(crow + (long)r * kD + dc + sc * 8, CsS + slot * 8192 + rb * 64);
        }
    };

    stageCs(0, 0);                                  // in flight under prologue

    // ---- prologue: stage As (fp32), Wsh (bf16), Msk; zero Pl ----
    const float* arow = s_out + (long)(b * kO + o0) * kD;
#pragma unroll
    for (int q = 0; q < 2; ++q) {      // 2 rows x 1024 = 512 float4
        const int tq = tid + q * 256;
        const int rr = tq >> 8, c4 = (tq & 255) * 4;
        *(float4*)&As[rr][c4] = *(const float4*)&arow[(long)rr * kD + c4];
    }
    {
        const float4 w4 = *(const float4*)&score_w[tid * 4];
        const unsigned p0 = (unsigned)(unsigned short)f2bf(w4.x)
                          | ((unsigned)(unsigned short)f2bf(w4.y) << 16);
        const unsigned p1 = (unsigned)(unsigned short)f2bf(w4.z)
                          | ((unsigned)(unsigned short)f2bf(w4.w) << 16);
        *(u32x2*)&Wsh[tid * 4] = u32x2{p0, p1};
    }
    if (tid < 128) Msk[tid] = mask[b * kI + tid];
    {
        short* pf = &Pl[0][0];                      // 16*136 = 2176 shorts
        for (int j = tid; j < 272; j += 256) *(short8*)(pf + j * 8) = short8{};
    }
    __syncthreads();                   // slot0 landed; LDS staged

    // ---- so[o] = sum_d s_out[o,d]*w[d]; waves 0,1 ----
    if (wv < 2) {
        const short8 wA = *(const short8*)&Wsh[ln * 16];
        const short8 wB = *(const short8*)&Wsh[ln * 16 + 8];
        float wf[16];
        b8tofs(wA, wf); b8tofs(wB, wf + 8);
        float acc = 0.0f;
#pragma unroll
        for (int q = 0; q < 4; ++q) {
            const float4 av = *(const float4*)&As[wv][ln * 16 + q * 4];
            acc = fmaf(av.x, wf[q*4+0], acc); acc = fmaf(av.y, wf[q*4+1], acc);
            acc = fmaf(av.z, wf[q*4+2], acc); acc = fmaf(av.w, wf[q*4+3], acc);
        }
#pragma unroll
        for (int d = 1; d < 64; d <<= 1) acc += __shfl_xor(acc, d, 64);
        if (ln == 0) so_sh[wv] = acc;
    }

    // ---- main loop: sa[o] = sum |av+c|*w, si = sum c*w; packed (i, i+64) ----
    f32x2 si2{0.0f, 0.0f};
    f32x2 sa2[2] = {f32x2{0.0f, 0.0f}, f32x2{0.0f, 0.0f}};
    const int kb = wv * 16;            // this wave's d-slice within each chunk

    int buf = 0;
    for (int c = 0; c < 16; ++c) {
        const int dc = c * 64;
        if (c < 15) stageCs(buf ^ 1, dc + 64);
        const short* Cb = CsS + buf * 8192;
        const int sc0 = ((wv * 2 + 0) ^ (ln & 7)) * 8;
        const int sc1 = ((wv * 2 + 1) ^ (ln & 7)) * 8;
        const short8 cA0 = *(const short8*)&Cb[ln * 64 + sc0];
        const short8 cA1 = *(const short8*)&Cb[ln * 64 + sc1];
        const short8 cB0 = *(const short8*)&Cb[(ln + 64) * 64 + sc0];
        const short8 cB1 = *(const short8*)&Cb[(ln + 64) * 64 + sc1];
        f32x2 c2[16];
        bpair(cA0, cB0, c2);
        bpair(cA1, cB1, c2 + 8);
        const short8 w0 = *(const short8*)&Wsh[dc + kb];      // broadcast
        const short8 w1 = *(const short8*)&Wsh[dc + kb + 8];
        float wr[16];
        b8tofs(w0, wr); b8tofs(w1, wr + 8);
        float av0[16], av1[16];
#pragma unroll
        for (int q = 0; q < 4; ++q) {
            *(float4*)&av0[q * 4] = *(const float4*)&As[0][dc + kb + q * 4];
            *(float4*)&av1[q * 4] = *(const float4*)&As[1][dc + kb + q * 4];
        }
#pragma unroll
        for (int d = 0; d < 16; ++d) {
            const f32x2 w2 = {wr[d], wr[d]};
            si2 += c2[d] * w2;
            const f32x2 x0 = c2[d] + f32x2{av0[d], av0[d]};
            const f32x2 x1 = c2[d] + f32x2{av1[d], av1[d]};
            sa2[0] += vabs2(x0) * w2;
            sa2[1] += vabs2(x1) * w2;
        }
        __syncthreads();               // drains gll16 vmcnt + protects Cs
        buf ^= 1;
    }

    // ---- stage final-GEMM B slot 0 (hides under partials + softmax) ----
    short* Bsh = (short*)CsPool;                    // [2][64][128] bf16
    const short* ctxb = ctxlin + (long)b * (kD * kI);
    auto stageB = [&](int half, int nc) {           // 4 gll16 per wave
#pragma unroll
        for (int it = 0; it < 4; ++it) {
            const int rb = wv * 16 + it * 4;        // dest row base (4 rows/call)
            const int r  = rb + (ln >> 4);
            const int n  = nc * 64 + r;
            const int sc = (ln & 15) ^ (r & 7);     // swizzled source chunk
            gll16(ctxb + (long)n * kI + sc * 8, Bsh + half * 8192 + rb * kI);
        }
    };
    stageB(0, 0);

#pragma unroll
    for (int o = 0; o < 2; ++o) {
        Ps[wv][o][ln]      = sa2[o].x;
        Ps[wv][o][ln + 64] = sa2[o].y;
    }
    Psi[wv][ln]      = si2.x;
    Psi[wv][ln + 64] = si2.y;
    __syncthreads();                   // partials visible; B slot0 landed

    // ---- combine + mask + softmax; waves 0,1 handle o-rows 0,1 ----
    if (wv < 2) {
        const int ow = wv;
        const float negInf = -__builtin_huge_valf();
        const float sb = score_b[0];
        const float siT0 = Psi[0][ln] + Psi[1][ln] + Psi[2][ln] + Psi[3][ln];
        const float siT1 = Psi[0][ln + 64] + Psi[1][ln + 64]
                         + Psi[2][ln + 64] + Psi[3][ln + 64];
        const float saT0 = Ps[0][ow][ln] + Ps[1][ow][ln]
                         + Ps[2][ow][ln] + Ps[3][ow][ln];
        const float saT1 = Ps[0][ow][ln + 64] + Ps[1][ow][ln + 64]
                         + Ps[2][ow][ln + 64] + Ps[3][ow][ln + 64];
        const float soV = so_sh[ow];
        float s0 = 0.505f * (soV + siT0) + 0.495f * saT0 + sb;
        float s1 = 0.505f * (soV + siT1) + 0.495f * saT1 + sb;
        if (Msk[ln]      != 0) s0 = negInf;
        if (Msk[ln + 64] != 0) s1 = negInf;

        float m = fmaxf(s0, s1);
#pragma unroll
        for (int d = 1; d < 64; d <<= 1) m = fmaxf(m, __shfl_xor(m, d, 64));
        const float e0 = __expf(s0 - m);
        const float e1 = __expf(s1 - m);
        float sum = e0 + e1;
#pragma unroll
        for (int d = 1; d < 64; d <<= 1) sum += __shfl_xor(sum, d, 64);
        const float inv = 1.0f / sum;

        const long rowoff = (long)(b * kO + o0 + ow) * kI;
        const float p0 = e0 * inv, p1 = e1 * inv;
        attn_f32[rowoff + ln]      = p0;
        attn_f32[rowoff + ln + 64] = p1;
        Pl[ow][ln]      = f2bf(p0);
        Pl[ow][ln + 64] = f2bf(p1);
    }
    __syncthreads();                   // Pl visible

    // ---- final GEMM: 16 steps of 64 n-rows, double-buffered ----
    int half = 0;
    for (int nc = 0; nc < 16; ++nc) {
        if (nc < 15) stageB(half ^ 1, nc + 1);
        const short* Bc = Bsh + half * 8192;
        f32x4 acc{};
#pragma unroll
        for (int ks = 0; ks < 4; ++ks) {
            const short8 a = *(const short8*)&Pl[fr][ks * 32 + fg * 8];
            const int sc = ((ks * 4 + fg) ^ (fr & 7)) * 8;
            const short8 bb = *(const short8*)&Bc[(wv * 16 + fr) * kI + sc];
            acc = __builtin_amdgcn_mfma_f32_16x16x32_bf16(a, bb, acc, 0, 0, 0);
        }
        if (fg == 0) {                 // real P-rows are m = 0,1
#pragma unroll
            for (int r = 0; r < 2; ++r) {
                const int n = nc * 64 + wv * 16 + fr;
                const long off = (long)(b * kO + o0 + r) * kD + n;
                out_main[off] = leaky(acc[r] + outlin[off]);
            }
        }
        __syncthreads();
        half ^= 1;
    }
}

} // namespace

extern "C" void kernel_launch(void* const* d_in, const int* in_sizes, int n_in,
                              void* d_out, int out_size, void* d_ws, size_t ws_size,
                              hipStream_t stream)
{
    const float* output  = (const float*)d_in[0];   // [B,O,D]
    const float* context = (const float*)d_in[1];   // [B,I,D]
    const int*   mask    = (const int*)d_in[2];     // [B,I]
    const float* w_out_w = (const float*)d_in[3];   // [D,D]
    const float* w_ctx_w = (const float*)d_in[4];   // [D,D]
    const float* w_b     = (const float*)d_in[5];   // [D]
    const float* score_w = (const float*)d_in[6];   // [D]
    const float* score_b = (const float*)d_in[7];   // scalar
    const float* lin_w   = (const float*)d_in[8];   // [2D,D]
    const float* lin_b   = (const float*)d_in[9];   // [D]

    float* out_main = (float*)d_out;                 // [B,O,D]
    float* out_attn = out_main + kOutAttnOff;        // [B,O,I]
    float* s_out    = out_main;                      // overlay: block reads its 2
                                                     // rows before rewriting them

    char* wp = (char*)d_ws;
    short* s_ctx16 = (short*)wp;  wp += (size_t)2 << 20;  // s_ctx bf16 [B*I][D]
    short* ob16    = (short*)wp;  wp += (size_t)2 << 20;  // output bf16
    short* cb16    = (short*)wp;  wp += (size_t)2 << 20;  // context bf16
    short* w1t     = (short*)wp;  wp += (size_t)2 << 20;  // w_out_w^T bf16
    short* w2t     = (short*)wp;  wp += (size_t)2 << 20;  // w_ctx_w^T bf16
    short* lint    = (short*)wp;  wp += (size_t)4 << 20;  // lin_w^T bf16 [1024][2048]
    float* outlin  = (float*)wp;  wp += (size_t)4 << 20;  // output@lin_bot+lin_b fp32
    short* ctxlin  = (short*)wp;                          // (ctx@lin_top)^T bf16 [b][1024][128]

    const dim3 blk(256);

    // 1) all conversions
    hipLaunchKernelGGL(conv_all, dim3(2048), blk, 0, stream,
        output, context, w_out_w, w_ctx_w, lin_w, ob16, cb16, w1t, w2t, lint);

    // 2) all input-independent GEMMs in one 512-block launch
    hipLaunchKernelGGL(mm_jobs, dim3(512), blk, 0, stream,
        ob16, cb16, w1t, w2t, lint, w_b, lin_b, s_out, s_ctx16, outlin, ctxlin);

    // 3) score + softmax + final GEMM fused (512 blocks, 3/CU)
    hipLaunchKernelGGL(score_final, dim3(8, 64), blk, 0, stream,
        s_out, s_ctx16, score_w, score_b, mask, ctxlin, outlin, out_main, out_attn);
}

// Round 12
// 60.901 us; speedup vs baseline: 3.9965x; 1.0409x over previous
//
#include <hip/hip_runtime.h>

namespace {

constexpr int kB = 8, kO = 128, kI = 128, kD = 1024;
constexpr long kOutAttnOff = (long)kB * kO * kD;   // 1,048,576 floats

typedef __attribute__((ext_vector_type(8))) short short8;  // 8 bf16 = 4 VGPR
typedef __attribute__((ext_vector_type(4))) float f32x4;
typedef __attribute__((ext_vector_type(2))) float f32x2;
typedef __attribute__((ext_vector_type(2))) unsigned u32x2;

__device__ __forceinline__ float leaky(float x) { return fmaxf(x, 0.01f * x); }

// fp32 -> bf16 round-to-nearest-even
__device__ __forceinline__ short f2bf(float f) {
    unsigned u = __builtin_bit_cast(unsigned, f);
    u += 0x7FFFu + ((u >> 16) & 1u);
    return (short)(u >> 16);
}
// short8 of bf16 -> 8 f32
__device__ __forceinline__ void b8tofs(const short8 v, float* f) {
    const unsigned* u = (const unsigned*)&v;
#pragma unroll
    for (int j = 0; j < 4; ++j) {
        f[2 * j]     = __builtin_bit_cast(float, u[j] << 16);
        f[2 * j + 1] = __builtin_bit_cast(float, u[j] & 0xffff0000u);
    }
}
// two short8 (same d-slice, rows i and i+64) -> f32x2 pairs {c_i, c_i64}
__device__ __forceinline__ void bpair(const short8 a, const short8 b, f32x2* p) {
    float fa[8], fb[8];
    b8tofs(a, fa); b8tofs(b, fb);
#pragma unroll
    for (int j = 0; j < 8; ++j) p[j] = f32x2{fa[j], fb[j]};
}
__device__ __forceinline__ f32x2 vabs2(f32x2 x) {
    u32x2 u = __builtin_bit_cast(u32x2, x);
    u &= 0x7fffffffu;
    return __builtin_bit_cast(f32x2, u);
}

// async global->LDS, 16B per lane. LDS dest = wave-uniform base + lane*16.
__device__ __forceinline__ void gll16(const void* g, void* l) {
    __builtin_amdgcn_global_load_lds(
        (const __attribute__((address_space(1))) int*)g,
        (__attribute__((address_space(3))) int*)l, 16, 0, 0);
}

// ---------------------------------------------------------------------------
// All input conversions in ONE kernel (r10 verbatim).
// ---------------------------------------------------------------------------
__global__ __launch_bounds__(256)
void conv_all(const float* __restrict__ output, const float* __restrict__ context,
              const float* __restrict__ w1, const float* __restrict__ w2,
              const float* __restrict__ lin,
              short* __restrict__ ob16, short* __restrict__ cb16,
              short* __restrict__ w1t, short* __restrict__ w2t,
              short* __restrict__ lint)
{
    __shared__ float T[64][68];
    const int bid = blockIdx.x, tid = threadIdx.x;

    if (bid < 1024) {                       // straight convert, 8 floats/thread
        const int idx = bid * 256 + tid;
        const float* src; short* dst; int i;
        if (idx < (1 << 17)) { src = output;  dst = ob16; i = idx; }
        else                 { src = context; dst = cb16; i = idx - (1 << 17); }
        const float4* s4 = (const float4*)src + (long)i * 2;
        const float4 v0 = s4[0], v1 = s4[1];
        short8 r;
        r[0] = f2bf(v0.x); r[1] = f2bf(v0.y); r[2] = f2bf(v0.z); r[3] = f2bf(v0.w);
        r[4] = f2bf(v1.x); r[5] = f2bf(v1.y); r[6] = f2bf(v1.z); r[7] = f2bf(v1.w);
        *(short8*)(dst + (long)i * 8) = r;
        return;
    }

    const int tb = bid - 1024;
    const float* src; short* dst; long C, R; int t2;
    if (tb < 256)      { src = w1;  dst = w1t;  R = 1024; C = 1024; t2 = tb; }
    else if (tb < 512) { src = w2;  dst = w2t;  R = 1024; C = 1024; t2 = tb - 256; }
    else               { src = lin; dst = lint; R = 2048; C = 1024; t2 = tb - 512; }
    const int tr = t2 >> 4, tc = t2 & 15;
    const int r = tid >> 2, q = tid & 3;

    const float* s = src + (long)(tr * 64 + r) * C + tc * 64 + q * 16;
    const float4 a0 = ((const float4*)s)[0];
    const float4 a1 = ((const float4*)s)[1];
    const float4 a2 = ((const float4*)s)[2];
    const float4 a3 = ((const float4*)s)[3];
    *(float4*)&T[r][q * 16 + 0]  = a0;
    *(float4*)&T[r][q * 16 + 4]  = a1;
    *(float4*)&T[r][q * 16 + 8]  = a2;
    *(float4*)&T[r][q * 16 + 12] = a3;
    __syncthreads();

    short8 o0, o1;
#pragma unroll
    for (int j = 0; j < 8; ++j)  o0[j] = f2bf(T[q * 16 + j][r]);
#pragma unroll
    for (int j = 0; j < 8; ++j)  o1[j] = f2bf(T[q * 16 + 8 + j][r]);
    short* dp = dst + (long)(tc * 64 + r) * R + tr * 64 + q * 16;
    *(short8*)dp       = o0;
    *((short8*)dp + 1) = o1;
}

// ---------------------------------------------------------------------------
// Fused independent-GEMM job table, v2: 64x64 tiles, 1024 blocks (4-5/CU),
// 32KB LDS double-buffer, gll16 staging w/ XOR chunk swizzle (rule #21),
// XCD-aware swizzle: logical tile t = (bid%8)*128 + bid/8, m-fastest order
// so the 16 m-tiles sharing a B n-strip land on one XCD's L2 (T1).
//   job0 (t<256):  s_out   = ob16 @ w1t^T + w_b        (fp32 [1024][1024])
//   job1 (t<512):  outlin  = ob16 @ lin_bot + lin_b    (fp32)
//   job2 (t<768):  s_ctx16 = cb16 @ w2t^T              (bf16 [1024][1024])
//   job3 (t>=768): ctxlin[b] = lint_top @ cb16[b]^T    (bf16 [1024][128])
// ---------------------------------------------------------------------------
__global__ __launch_bounds__(256, 4)
void mm_jobs(const short* __restrict__ ob16, const short* __restrict__ cb16,
             const short* __restrict__ w1t, const short* __restrict__ w2t,
             const short* __restrict__ lint,
             const float* __restrict__ w_b, const float* __restrict__ lin_b,
             float* __restrict__ s_out, short* __restrict__ s_ctx16,
             float* __restrict__ outlin, short* __restrict__ ctxlin)
{
    __shared__ short As[2][64][64];
    __shared__ short Bs[2][64][64];
    const int tid = threadIdx.x;
    const int t = (blockIdx.x & 7) * 128 + (blockIdx.x >> 3);   // XCD swizzle
    const int lane = tid & 63, w = tid >> 6;

    const short *Ap, *Bp;
    int lda, ldb, bm, bn, ldc;
    const float* bias = nullptr;
    float* Cf = nullptr;
    short* Ch = nullptr;

    if (t < 768) {
        const int job = t >> 8, tl = t & 255;
        bm = (tl & 15) * 64;            // m fastest: B n-strip shared on-XCD
        bn = (tl >> 4) * 64;
        lda = 1024; ldb = 1024; ldc = 1024;
        if (job == 0)      { Ap = ob16; Bp = w1t;         bias = w_b;   Cf = s_out;   }
        else if (job == 1) { Ap = ob16; Bp = lint + 1024; ldb = 2048; bias = lin_b; Cf = outlin; }
        else               { Ap = cb16; Bp = w2t;                       Ch = s_ctx16; }
    } else {
        const int tl = t - 768, bz = tl >> 5, t2 = tl & 31;
        bm = (t2 & 15) * 64;            // m = d tiles
        bn = (t2 >> 4) * 64;            // n = i tiles (2)
        Ap = lint; lda = 2048;
        Bp = cb16 + (long)bz * (kI * kD); ldb = 1024;
        Ch = ctxlin + (long)bz * (kD * kI); ldc = 128;
    }

    const int m0 = (w >> 1) * 32, n0 = (w & 1) * 32;
    const int fr = lane & 15, fcol = lane >> 4, sl = lane & 7;
    const int r8 = lane >> 3;
    const int sw8 = ((lane & 7) ^ r8) * 8;   // swizzled source col (shorts)
    const int w16 = w * 16;

    f32x4 acc[2][2] = {};

    auto stage = [&](int buf, int k0) {      // 4 gll16 per wave
        const short* ga = Ap + (long)(bm + w16 + r8) * lda + k0 + sw8;
        gll16(ga,                 &As[buf][w16][0]);
        gll16(ga + 8 * (long)lda, &As[buf][w16 + 8][0]);
        const short* gb = Bp + (long)(bn + w16 + r8) * ldb + k0 + sw8;
        gll16(gb,                 &Bs[buf][w16][0]);
        gll16(gb + 8 * (long)ldb, &Bs[buf][w16 + 8][0]);
    };

    stage(0, 0);
    __syncthreads();
    int cur = 0;
    for (int s = 0; s < 16; ++s) {
        if (s < 15) stage(cur ^ 1, (s + 1) << 6);
#pragma unroll
        for (int ks8 = 0; ks8 < 8; ks8 += 4) {      // ks = 0, 32
            const int sa = ((ks8 + fcol) ^ sl) * 8; // swizzled read col (shorts)
            short8 a[2], b[2];
#pragma unroll
            for (int mi = 0; mi < 2; ++mi)
                a[mi] = *(const short8*)&As[cur][m0 + mi * 16 + fr][sa];
#pragma unroll
            for (int ni = 0; ni < 2; ++ni)
                b[ni] = *(const short8*)&Bs[cur][n0 + ni * 16 + fr][sa];
#pragma unroll
            for (int mi = 0; mi < 2; ++mi)
#pragma unroll
                for (int ni = 0; ni < 2; ++ni)
                    acc[mi][ni] = __builtin_amdgcn_mfma_f32_16x16x32_bf16(
                        a[mi], b[ni], acc[mi][ni], 0, 0, 0);
        }
        __syncthreads();
        cur ^= 1;
    }

    float bv[2] = {0, 0};
    if (bias) {
#pragma unroll
        for (int ni = 0; ni < 2; ++ni) bv[ni] = bias[bn + n0 + ni * 16 + fr];
    }
#pragma unroll
    for (int mi = 0; mi < 2; ++mi)
#pragma unroll
        for (int ni = 0; ni < 2; ++ni)
#pragma unroll
            for (int r = 0; r < 4; ++r) {
                const int row = bm + m0 + mi * 16 + ((lane >> 4) << 2) + r;
                const int col = bn + n0 + ni * 16 + fr;
                const float v = acc[mi][ni][r] + bv[ni];
                if (Ch) Ch[(long)row * ldc + col] = f2bf(v);
                else    Cf[(long)row * ldc + col] = v;
            }
}

// ---------------------------------------------------------------------------
// Fused score + mask + softmax + final GEMM (r10 verbatim, passing).
// Grid (8, 64) = 512 blocks (o-pairs), 4 waves, ~52.8KB LDS -> 3 blocks/CU.
// ---------------------------------------------------------------------------
__global__ __launch_bounds__(256, 3)
void score_final(const float* __restrict__ s_out, const short* __restrict__ s_ctx16,
                 const float* __restrict__ score_w, const float* __restrict__ score_b,
                 const int* __restrict__ mask, const short* __restrict__ ctxlin,
                 const float* __restrict__ outlin, float* __restrict__ out_main,
                 float* __restrict__ attn_f32)
{
    __shared__ float As[2][1032];                   // 2 o-rows fp32 (8.25KB)
    __shared__ __align__(16) char CsPool[32768];    // 2 x 16KB slots (Cs / B)
    __shared__ short Wsh[1032];                     // score_w bf16 (2KB)
    __shared__ float Ps[4][2][128];                 // sa partials (4KB)
    __shared__ float Psi[4][128];                   // si partials (2KB)
    __shared__ float so_sh[2];
    __shared__ int   Msk[128];
    __shared__ __align__(16) short Pl[16][136];     // P rows padded to 16 (4.25KB)

    short* CsS = (short*)CsPool;                    // slot s: CsS + s*8192 shorts
    const int b   = blockIdx.x;
    const int o0  = blockIdx.y * 2;
    const int tid = threadIdx.x;
    const int wv  = tid >> 6;          // d-quarter (wave-uniform)
    const int ln  = tid & 63;          // i low half; also owns i+64
    const int fr  = ln & 15, fg = ln >> 4;

    const short* crow = s_ctx16 + (long)b * kI * kD;
    auto stageCs = [&](int slot, int dc) {          // 4 gll16 per wave
#pragma unroll
        for (int it = 0; it < 4; ++it) {
            const int rb = wv * 32 + it * 8;        // dest row base (8 rows/call)
            const int r  = rb + (ln >> 3);
            const int sc = (ln & 7) ^ (r & 7);      // swizzled source chunk
            gll16(crow + (long)r * kD + dc + sc * 8, CsS + slot * 8192 + rb * 64);
        }
    };

    stageCs(0, 0);                                  // in flight under prologue

    // ---- prologue: stage As (fp32), Wsh (bf16), Msk; zero Pl ----
    const float* arow = s_out + (long)(b * kO + o0) * kD;
#pragma unroll
    for (int q = 0; q < 2; ++q) {      // 2 rows x 1024 = 512 float4
        const int tq = tid + q * 256;
        const int rr = tq >> 8, c4 = (tq & 255) * 4;
        *(float4*)&As[rr][c4] = *(const float4*)&arow[(long)rr * kD + c4];
    }
    {
        const float4 w4 = *(const float4*)&score_w[tid * 4];
        const unsigned p0 = (unsigned)(unsigned short)f2bf(w4.x)
                          | ((unsigned)(unsigned short)f2bf(w4.y) << 16);
        const unsigned p1 = (unsigned)(unsigned short)f2bf(w4.z)
                          | ((unsigned)(unsigned short)f2bf(w4.w) << 16);
        *(u32x2*)&Wsh[tid * 4] = u32x2{p0, p1};
    }
    if (tid < 128) Msk[tid] = mask[b * kI + tid];
    {
        short* pf = &Pl[0][0];                      // 16*136 = 2176 shorts
        for (int j = tid; j < 272; j += 256) *(short8*)(pf + j * 8) = short8{};
    }
    __syncthreads();                   // slot0 landed; LDS staged

    // ---- so[o] = sum_d s_out[o,d]*w[d]; waves 0,1 ----
    if (wv < 2) {
        const short8 wA = *(const short8*)&Wsh[ln * 16];
        const short8 wB = *(const short8*)&Wsh[ln * 16 + 8];
        float wf[16];
        b8tofs(wA, wf); b8tofs(wB, wf + 8);
        float acc = 0.0f;
#pragma unroll
        for (int q = 0; q < 4; ++q) {
            const float4 av = *(const float4*)&As[wv][ln * 16 + q * 4];
            acc = fmaf(av.x, wf[q*4+0], acc); acc = fmaf(av.y, wf[q*4+1], acc);
            acc = fmaf(av.z, wf[q*4+2], acc); acc = fmaf(av.w, wf[q*4+3], acc);
        }
#pragma unroll
        for (int d = 1; d < 64; d <<= 1) acc += __shfl_xor(acc, d, 64);
        if (ln == 0) so_sh[wv] = acc;
    }

    // ---- main loop: sa[o] = sum |av+c|*w, si = sum c*w; packed (i, i+64) ----
    f32x2 si2{0.0f, 0.0f};
    f32x2 sa2[2] = {f32x2{0.0f, 0.0f}, f32x2{0.0f, 0.0f}};
    const int kb = wv * 16;            // this wave's d-slice within each chunk

    int buf = 0;
    for (int c = 0; c < 16; ++c) {
        const int dc = c * 64;
        if (c < 15) stageCs(buf ^ 1, dc + 64);
        const short* Cb = CsS + buf * 8192;
        const int sc0 = ((wv * 2 + 0) ^ (ln & 7)) * 8;
        const int sc1 = ((wv * 2 + 1) ^ (ln & 7)) * 8;
        const short8 cA0 = *(const short8*)&Cb[ln * 64 + sc0];
        const short8 cA1 = *(const short8*)&Cb[ln * 64 + sc1];
        const short8 cB0 = *(const short8*)&Cb[(ln + 64) * 64 + sc0];
        const short8 cB1 = *(const short8*)&Cb[(ln + 64) * 64 + sc1];
        f32x2 c2[16];
        bpair(cA0, cB0, c2);
        bpair(cA1, cB1, c2 + 8);
        const short8 w0 = *(const short8*)&Wsh[dc + kb];      // broadcast
        const short8 w1 = *(const short8*)&Wsh[dc + kb + 8];
        float wr[16];
        b8tofs(w0, wr); b8tofs(w1, wr + 8);
        float av0[16], av1[16];
#pragma unroll
        for (int q = 0; q < 4; ++q) {
            *(float4*)&av0[q * 4] = *(const float4*)&As[0][dc + kb + q * 4];
            *(float4*)&av1[q * 4] = *(const float4*)&As[1][dc + kb + q * 4];
        }
#pragma unroll
        for (int d = 0; d < 16; ++d) {
            const f32x2 w2 = {wr[d], wr[d]};
            si2 += c2[d] * w2;
            const f32x2 x0 = c2[d] + f32x2{av0[d], av0[d]};
            const f32x2 x1 = c2[d] + f32x2{av1[d], av1[d]};
            sa2[0] += vabs2(x0) * w2;
            sa2[1] += vabs2(x1) * w2;
        }
        __syncthreads();               // drains gll16 vmcnt + protects Cs
        buf ^= 1;
    }

    // ---- stage final-GEMM B slot 0 (hides under partials + softmax) ----
    short* Bsh = (short*)CsPool;                    // [2][64][128] bf16
    const short* ctxb = ctxlin + (long)b * (kD * kI);
    auto stageB = [&](int half, int nc) {           // 4 gll16 per wave
#pragma unroll
        for (int it = 0; it < 4; ++it) {
            const int rb = wv * 16 + it * 4;        // dest row base (4 rows/call)
            const int r  = rb + (ln >> 4);
            const int n  = nc * 64 + r;
            const int sc = (ln & 15) ^ (r & 7);     // swizzled source chunk
            gll16(ctxb + (long)n * kI + sc * 8, Bsh + half * 8192 + rb * kI);
        }
    };
    stageB(0, 0);

#pragma unroll
    for (int o = 0; o < 2; ++o) {
        Ps[wv][o][ln]      = sa2[o].x;
        Ps[wv][o][ln + 64] = sa2[o].y;
    }
    Psi[wv][ln]      = si2.x;
    Psi[wv][ln + 64] = si2.y;
    __syncthreads();                   // partials visible; B slot0 landed

    // ---- combine + mask + softmax; waves 0,1 handle o-rows 0,1 ----
    if (wv < 2) {
        const int ow = wv;
        const float negInf = -__builtin_huge_valf();
        const float sb = score_b[0];
        const float siT0 = Psi[0][ln] + Psi[1][ln] + Psi[2][ln] + Psi[3][ln];
        const float siT1 = Psi[0][ln + 64] + Psi[1][ln + 64]
                         + Psi[2][ln + 64] + Psi[3][ln + 64];
        const float saT0 = Ps[0][ow][ln] + Ps[1][ow][ln]
                         + Ps[2][ow][ln] + Ps[3][ow][ln];
        const float saT1 = Ps[0][ow][ln + 64] + Ps[1][ow][ln + 64]
                         + Ps[2][ow][ln + 64] + Ps[3][ow][ln + 64];
        const float soV = so_sh[ow];
        float s0 = 0.505f * (soV + siT0) + 0.495f * saT0 + sb;
        float s1 = 0.505f * (soV + siT1) + 0.495f * saT1 + sb;
        if (Msk[ln]      != 0) s0 = negInf;
        if (Msk[ln + 64] != 0) s1 = negInf;

        float m = fmaxf(s0, s1);
#pragma unroll
        for (int d = 1; d < 64; d <<= 1) m = fmaxf(m, __shfl_xor(m, d, 64));
        const float e0 = __expf(s0 - m);
        const float e1 = __expf(s1 - m);
        float sum = e0 + e1;
#pragma unroll
        for (int d = 1; d < 64; d <<= 1) sum += __shfl_xor(sum, d, 64);
        const float inv = 1.0f / sum;

        const long rowoff = (long)(b * kO + o0 + ow) * kI;
        const float p0 = e0 * inv, p1 = e1 * inv;
        attn_f32[rowoff + ln]      = p0;
        attn_f32[rowoff + ln + 64] = p1;
        Pl[ow][ln]      = f2bf(p0);
        Pl[ow][ln + 64] = f2bf(p1);
    }
    __syncthreads();                   // Pl visible

    // ---- final GEMM: 16 steps of 64 n-rows, double-buffered ----
    int half = 0;
    for (int nc = 0; nc < 16; ++nc) {
        if (nc < 15) stageB(half ^ 1, nc + 1);
        const short* Bc = Bsh + half * 8192;
        f32x4 acc{};
#pragma unroll
        for (int ks = 0; ks < 4; ++ks) {
            const short8 a = *(const short8*)&Pl[fr][ks * 32 + fg * 8];
            const int sc = ((ks * 4 + fg) ^ (fr & 7)) * 8;
            const short8 bb = *(const short8*)&Bc[(wv * 16 + fr) * kI + sc];
            acc = __builtin_amdgcn_mfma_f32_16x16x32_bf16(a, bb, acc, 0, 0, 0);
        }
        if (fg == 0) {                 // real P-rows are m = 0,1
#pragma unroll
            for (int r = 0; r < 2; ++r) {
                const int n = nc * 64 + wv * 16 + fr;
                const long off = (long)(b * kO + o0 + r) * kD + n;
                out_main[off] = leaky(acc[r] + outlin[off]);
            }
        }
        __syncthreads();
        half ^= 1;
    }
}

} // namespace

extern "C" void kernel_launch(void* const* d_in, const int* in_sizes, int n_in,
                              void* d_out, int out_size, void* d_ws, size_t ws_size,
                              hipStream_t stream)
{
    const float* output  = (const float*)d_in[0];   // [B,O,D]
    const float* context = (const float*)d_in[1];   // [B,I,D]
    const int*   mask    = (const int*)d_in[2];     // [B,I]
    const float* w_out_w = (const float*)d_in[3];   // [D,D]
    const float* w_ctx_w = (const float*)d_in[4];   // [D,D]
    const float* w_b     = (const float*)d_in[5];   // [D]
    const float* score_w = (const float*)d_in[6];   // [D]
    const float* score_b = (const float*)d_in[7];   // scalar
    const float* lin_w   = (const float*)d_in[8];   // [2D,D]
    const float* lin_b   = (const float*)d_in[9];   // [D]

    float* out_main = (float*)d_out;                 // [B,O,D]
    float* out_attn = out_main + kOutAttnOff;        // [B,O,I]
    float* s_out    = out_main;                      // overlay: block reads its 2
                                                     // rows before rewriting them

    char* wp = (char*)d_ws;
    short* s_ctx16 = (short*)wp;  wp += (size_t)2 << 20;  // s_ctx bf16 [B*I][D]
    short* ob16    = (short*)wp;  wp += (size_t)2 << 20;  // output bf16
    short* cb16    = (short*)wp;  wp += (size_t)2 << 20;  // context bf16
    short* w1t     = (short*)wp;  wp += (size_t)2 << 20;  // w_out_w^T bf16
    short* w2t     = (short*)wp;  wp += (size_t)2 << 20;  // w_ctx_w^T bf16
    short* lint    = (short*)wp;  wp += (size_t)4 << 20;  // lin_w^T bf16 [1024][2048]
    float* outlin  = (float*)wp;  wp += (size_t)4 << 20;  // output@lin_bot+lin_b fp32
    short* ctxlin  = (short*)wp;                          // (ctx@lin_top)^T bf16 [b][1024][128]

    const dim3 blk(256);

    // 1) all conversions
    hipLaunchKernelGGL(conv_all, dim3(2048), blk, 0, stream,
        output, context, w_out_w, w_ctx_w, lin_w, ob16, cb16, w1t, w2t, lint);

    // 2) all input-independent GEMMs: 64x64 tiles, 1024 blocks, XCD-swizzled
    hipLaunchKernelGGL(mm_jobs, dim3(1024), blk, 0, stream,
        ob16, cb16, w1t, w2t, lint, w_b, lin_b, s_out, s_ctx16, outlin, ctxlin);

    // 3) score + softmax + final GEMM fused (512 blocks, 3/CU)
    hipLaunchKernelGGL(score_final, dim3(8, 64), blk, 0, stream,
        s_out, s_ctx16, score_w, score_b, mask, ctxlin, outlin, out_main, out_attn);
}